// Round 2
// baseline (982.729 us; speedup 1.0000x reference)
//
#include <hip/hip_runtime.h>
#include <cstdint>

#define AS1 __attribute__((address_space(1)))
#define AS3 __attribute__((address_space(3)))

typedef __bf16 bf16x8 __attribute__((ext_vector_type(8)));
typedef __bf16 bf16x4 __attribute__((ext_vector_type(4)));
typedef float  f32x4  __attribute__((ext_vector_type(4)));

// ---------------------------------------------------------------------------
// Elementwise / transpose kernels
// ---------------------------------------------------------------------------

// Copy input [B][1024][4096] fp32 into top half of out [B][2048][4096],
// and zero the bottom (attention) half so PV split-K can atomicAdd into it.
__global__ void copy_zero_k(const float4* __restrict__ in, float4* __restrict__ out) {
  int i = blockIdx.x * 256 + threadIdx.x;       // 2 * 4194304 total
  if (i < 4194304) {                            // copy input -> top half
    int b = i >> 20;                            // 1048576 float4 per batch slice
    int r = i & 1048575;
    out[(long)b * 2097152 + r] = in[i];
  } else {                                      // zero bottom half
    int z = i - 4194304;
    int b = z >> 20;
    int r = z & 1048575;
    out[(long)b * 2097152 + 1048576 + r] = make_float4(0.f, 0.f, 0.f, 0.f);
  }
}

// input slice [1024][4096] fp32 -> xb [4096][1024] bf16 (tiled transpose)
__global__ void transpose_x_k(const float* __restrict__ in, __bf16* __restrict__ out) {
  __shared__ float t[32][33];
  int s0 = blockIdx.x * 32, c0 = blockIdx.y * 32;
  int tx = threadIdx.x, ty = threadIdx.y;
#pragma unroll
  for (int i = 0; i < 4; i++)
    t[ty + i * 8][tx] = in[(c0 + ty + i * 8) * 4096 + s0 + tx];
  __syncthreads();
#pragma unroll
  for (int i = 0; i < 4; i++)
    out[(s0 + ty + i * 8) * 1024 + c0 + tx] = (__bf16)t[tx][ty + i * 8];
}

// Wq/Wk/Wv [1024][1024] fp32 -> Wt [3072][1024] bf16, transposed ([n][c]),
// with 1/sqrt(K)=1/32 folded into the Q slice.
__global__ void transpose_w_k(const float* __restrict__ Wq, const float* __restrict__ Wk,
                              const float* __restrict__ Wv, __bf16* __restrict__ Wt) {
  __shared__ float t[32][33];
  int sel = blockIdx.z;
  const float* W = sel == 0 ? Wq : (sel == 1 ? Wk : Wv);
  float scale = sel == 0 ? 0.03125f : 1.0f;
  int n0 = blockIdx.x * 32, c0 = blockIdx.y * 32;
  int tx = threadIdx.x, ty = threadIdx.y;
#pragma unroll
  for (int i = 0; i < 4; i++)
    t[ty + i * 8][tx] = W[(c0 + ty + i * 8) * 1024 + n0 + tx];
  __syncthreads();
#pragma unroll
  for (int i = 0; i < 4; i++)
    Wt[(sel * 1024 + n0 + ty + i * 8) * 1024 + c0 + tx] = (__bf16)(t[tx][ty + i * 8] * scale);
}

__global__ void bcat_k(const float* __restrict__ bq, const float* __restrict__ bk,
                       const float* __restrict__ bv, float* __restrict__ bcat) {
  int n = blockIdx.x * 256 + threadIdx.x;       // 3072 total
  float v = n < 1024 ? bq[n] * 0.03125f : (n < 2048 ? bk[n - 1024] : bv[n - 2048]);
  bcat[n] = v;
}

// ---------------------------------------------------------------------------
// 128x128 bf16 MFMA GEMM core (m97 structure): 256 threads = 4 waves in 2x2,
// each wave 4x4 fragments of 16x16x32. A row-major [M][K], B as B^T row-major
// [N][K]. acc[m][n] += sum_{k in [kbeg,kend)} A[m,k]*B[n,k].
// ---------------------------------------------------------------------------
__device__ __forceinline__ void gemm128_core(const __bf16* __restrict__ A, int lda, int m0,
                                             const __bf16* __restrict__ B, int ldb, int n0,
                                             int kbeg, int kend, __bf16* As, __bf16* Bs,
                                             f32x4 acc[4][4]) {
  const int tid = threadIdx.x;
  const int lane = tid & 63;
  const int wid = tid >> 6;
  const int wr = wid >> 1, wc = wid & 1;
  const int lr = lane & 15;
  const int lk = (lane >> 4) << 3;
  const int srow = tid >> 2;            // 0..63
  const int skq = (tid & 3) << 3;       // 0,8,16,24
  const __bf16* ga = A + (long)(m0 + srow) * lda + skq;
  const __bf16* gb = B + (long)(n0 + srow) * ldb + skq;

  for (int k0 = kbeg; k0 < kend; k0 += 32) {
    __builtin_amdgcn_global_load_lds((const AS1 void*)(ga + k0),            (AS3 void*)(As + tid * 8),        16, 0, 0);
    __builtin_amdgcn_global_load_lds((const AS1 void*)(ga + k0 + 64 * lda), (AS3 void*)(As + tid * 8 + 2048), 16, 0, 0);
    __builtin_amdgcn_global_load_lds((const AS1 void*)(gb + k0),            (AS3 void*)(Bs + tid * 8),        16, 0, 0);
    __builtin_amdgcn_global_load_lds((const AS1 void*)(gb + k0 + 64 * ldb), (AS3 void*)(Bs + tid * 8 + 2048), 16, 0, 0);
    __syncthreads();
    bf16x8 af[4], bfr[4];
#pragma unroll
    for (int m = 0; m < 4; m++)
      af[m] = *(const bf16x8*)(As + (wr * 64 + m * 16 + lr) * 32 + lk);
#pragma unroll
    for (int n = 0; n < 4; n++)
      bfr[n] = *(const bf16x8*)(Bs + (wc * 64 + n * 16 + lr) * 32 + lk);
#pragma unroll
    for (int m = 0; m < 4; m++)
#pragma unroll
      for (int n = 0; n < 4; n++)
        acc[m][n] = __builtin_amdgcn_mfma_f32_16x16x32_bf16(af[m], bfr[n], acc[m][n], 0, 0, 0);
    __syncthreads();
  }
}

// ---------------------------------------------------------------------------
// QKV fused projection: [4096 x 3072] = xb[4096x1024] @ Wt^T
// n<1024 -> Q (pre-scaled 1/32), n<2048 -> K, else V stored transposed [v][s]
// ---------------------------------------------------------------------------
__global__ void qkv_gemm_k(const __bf16* __restrict__ xb, const __bf16* __restrict__ Wt,
                           const float* __restrict__ bcat, __bf16* __restrict__ Qb,
                           __bf16* __restrict__ Kb, __bf16* __restrict__ Vt) {
  __shared__ __bf16 As[4096], Bs[4096];
  f32x4 acc[4][4] = {};
  int m0 = blockIdx.y * 128, n0 = blockIdx.x * 128;
  gemm128_core(xb, 1024, m0, Wt, 1024, n0, 0, 1024, As, Bs, acc);

  const int lane = threadIdx.x & 63;
  const int wid = threadIdx.x >> 6;
  const int wr = wid >> 1, wc = wid & 1;
  const int lr = lane & 15;
  const int lg = (lane >> 4) * 4;
#pragma unroll
  for (int m = 0; m < 4; m++) {
    int rs = m0 + wr * 64 + m * 16 + lg;
#pragma unroll
    for (int n = 0; n < 4; n++) {
      int col = n0 + wc * 64 + n * 16 + lr;
      float bias = bcat[col];
      if (col < 1024) {
#pragma unroll
        for (int r = 0; r < 4; r++)
          Qb[(rs + r) * 1024 + col] = (__bf16)(acc[m][n][r] + bias);
      } else if (col < 2048) {
#pragma unroll
        for (int r = 0; r < 4; r++)
          Kb[(rs + r) * 1024 + (col - 1024)] = (__bf16)(acc[m][n][r] + bias);
      } else {
        bf16x4 t4;
#pragma unroll
        for (int r = 0; r < 4; r++) t4[r] = (__bf16)(acc[m][n][r] + bias);
        *(bf16x4*)(Vt + (long)(col - 2048) * 4096 + rs) = t4;
      }
    }
  }
}

// ---------------------------------------------------------------------------
// QK^T: scores[s][t] = Q[s,:]·K[t,:]  (Q pre-scaled by 1/32). Upper-tri tiles skipped.
// Score row stride = 4096 floats (16KB).
// ---------------------------------------------------------------------------
__global__ void qk_gemm_k(const __bf16* __restrict__ Qb, const __bf16* __restrict__ Kb,
                          float* __restrict__ sc) {
  if (blockIdx.x > blockIdx.y) return;  // tile fully above diagonal
  __shared__ __bf16 As[4096], Bs[4096];
  f32x4 acc[4][4] = {};
  int m0 = blockIdx.y * 128, n0 = blockIdx.x * 128;
  gemm128_core(Qb, 1024, m0, Kb, 1024, n0, 0, 1024, As, Bs, acc);

  const int lane = threadIdx.x & 63;
  const int wid = threadIdx.x >> 6;
  const int wr = wid >> 1, wc = wid & 1;
  const int lr = lane & 15;
  const int lg = (lane >> 4) * 4;
#pragma unroll
  for (int m = 0; m < 4; m++) {
    int rs = m0 + wr * 64 + m * 16 + lg;
#pragma unroll
    for (int n = 0; n < 4; n++) {
      int col = n0 + wc * 64 + n * 16 + lr;
#pragma unroll
      for (int r = 0; r < 4; r++)
        sc[(long)(rs + r) * 4096 + col] = acc[m][n][r];
    }
  }
}

// ---------------------------------------------------------------------------
// Row softmax with causal mask + alibi. P (bf16, 4096 entries, zeros above
// diagonal) written IN PLACE into the second 8KB half of each 16KB score row.
// ---------------------------------------------------------------------------
__global__ void softmax_k(float* __restrict__ sc, const float* __restrict__ frame,
                          const float* __restrict__ alibi_p) {
  __shared__ float buf[4096];
  __shared__ float red[4];
  int s = blockIdx.x;
  float* srow = sc + (long)s * 4096;
  __bf16* prow = (__bf16*)(srow + 2048);
  int tid = threadIdx.x, lane = tid & 63, wid = tid >> 6;
  float sig = 1.0f / (1.0f + __expf(-alibi_p[0]));
  float fs = frame[s];
  int n = s + 1;

  float mx = -3.4e38f;
  for (int t = tid; t < n; t += 256) {
    float v = srow[t] - sig * fabsf(frame[t] - fs);
    buf[t] = v;
    mx = fmaxf(mx, v);
  }
#pragma unroll
  for (int o = 32; o; o >>= 1) mx = fmaxf(mx, __shfl_xor(mx, o, 64));
  if (lane == 0) red[wid] = mx;
  __syncthreads();
  mx = fmaxf(fmaxf(red[0], red[1]), fmaxf(red[2], red[3]));

  float sum = 0.0f;
  for (int t = tid; t < n; t += 256) {
    float e = __expf(buf[t] - mx);
    buf[t] = e;
    sum += e;
  }
#pragma unroll
  for (int o = 32; o; o >>= 1) sum += __shfl_xor(sum, o, 64);
  __syncthreads();
  if (lane == 0) red[wid] = sum;
  __syncthreads();
  sum = red[0] + red[1] + red[2] + red[3];
  float inv = 1.0f / sum;

  for (int t = tid; t < 4096; t += 256) {
    float p = (t < n) ? buf[t] * inv : 0.0f;
    prow[t] = (__bf16)p;
  }
}

// ---------------------------------------------------------------------------
// PV split-K: out[v][s] += sum_{t in chunk} P[s,t] * Vt[v,t], via f32 atomics.
// Chunk width 1024. blockIdx.x = n-tile (v), blockIdx.y = linear (m-tile, chunk).
// Mapping: m-tile mi has floor(mi/8)+1 chunks; group g (mi=8g..8g+7) starts at
// linear offset 4g(g+1); total 80. P row stride = 8192 bf16 (16KB).
// ---------------------------------------------------------------------------
__global__ void pv_gemm_k(const __bf16* __restrict__ P, const __bf16* __restrict__ Vt,
                          float* __restrict__ outb) {
  int y = blockIdx.y;
  int g = 0;
  while (y >= 4 * (g + 1) * (g + 2)) g++;
  int r0 = y - 4 * g * (g + 1);
  int mi = 8 * g + r0 / (g + 1);
  int j = r0 - (r0 / (g + 1)) * (g + 1);

  __shared__ __bf16 As[4096], Bs[4096];
  f32x4 acc[4][4] = {};
  int m0 = mi * 128, n0 = blockIdx.x * 128;
  int kbeg = j * 1024;
  int kend = min((j + 1) * 1024, m0 + 128);   // causal bound
  gemm128_core(P, 8192, m0, Vt, 4096, n0, kbeg, kend, As, Bs, acc);

  const int lane = threadIdx.x & 63;
  const int wid = threadIdx.x >> 6;
  const int wr = wid >> 1, wc = wid & 1;
  const int lr = lane & 15;
  const int lg = (lane >> 4) * 4;
#pragma unroll
  for (int m = 0; m < 4; m++) {
    int rs = m0 + wr * 64 + m * 16 + lg;
#pragma unroll
    for (int n = 0; n < 4; n++) {
      int col = n0 + wc * 64 + n * 16 + lr;   // v index
#pragma unroll
      for (int r = 0; r < 4; r++)
        atomicAdd(&outb[(long)col * 4096 + rs + r], acc[m][n][r]);
    }
  }
}

// ---------------------------------------------------------------------------

static inline char* align256(char* p) {
  return (char*)(((uintptr_t)p + 255) & ~(uintptr_t)255);
}

extern "C" void kernel_launch(void* const* d_in, const int* in_sizes, int n_in,
                              void* d_out, int out_size, void* d_ws, size_t ws_size,
                              hipStream_t stream) {
  const float* input = (const float*)d_in[0];   // [4][1024][4096]
  const float* frame = (const float*)d_in[1];   // [4096]
  const float* Wq = (const float*)d_in[2];
  const float* bq = (const float*)d_in[3];
  const float* Wk = (const float*)d_in[4];
  const float* bk = (const float*)d_in[5];
  const float* Wv = (const float*)d_in[6];
  const float* bv = (const float*)d_in[7];
  const float* alibi = (const float*)d_in[8];
  float* out = (float*)d_out;                   // [4][2048][4096]

  char* p = (char*)d_ws;
  __bf16* Wt = (__bf16*)p;  p += (size_t)3072 * 1024 * 2;
  float* bcat = (float*)p;  p += 3072 * 4;       p = align256(p);
  __bf16* xb = (__bf16*)p;  p += (size_t)4096 * 1024 * 2;  p = align256(p);
  __bf16* Qb = (__bf16*)p;  p += (size_t)4096 * 1024 * 2;  p = align256(p);
  __bf16* Kb = (__bf16*)p;  p += (size_t)4096 * 1024 * 2;  p = align256(p);
  __bf16* Vt = (__bf16*)p;  p += (size_t)4096 * 1024 * 2;  p = align256(p);
  float* sc = (float*)p;    // [4096][4096] fp32, 67MB; P aliased into row second halves

  transpose_w_k<<<dim3(32, 32, 3), dim3(32, 8), 0, stream>>>(Wq, Wk, Wv, Wt);
  bcat_k<<<12, 256, 0, stream>>>(bq, bk, bv, bcat);
  copy_zero_k<<<32768, 256, 0, stream>>>((const float4*)input, (float4*)out);

  for (int b = 0; b < 4; b++) {
    const float* inb = input + (size_t)b * 1024 * 4096;
    transpose_x_k<<<dim3(128, 32), dim3(32, 8), 0, stream>>>(inb, xb);
    qkv_gemm_k<<<dim3(24, 32), 256, 0, stream>>>(xb, Wt, bcat, Qb, Kb, Vt);
    qk_gemm_k<<<dim3(32, 32), 256, 0, stream>>>(Qb, Kb, sc);
    softmax_k<<<4096, 256, 0, stream>>>(sc, frame, alibi);
    pv_gemm_k<<<dim3(8, 80), 256, 0, stream>>>((const __bf16*)((char*)sc + 8192), Vt,
                                               out + ((size_t)b * 2048 + 1024) * 4096);
  }
}

// Round 3
// 564.200 us; speedup vs baseline: 1.7418x; 1.7418x over previous
//
#include <hip/hip_runtime.h>
#include <cstdint>

#define AS1 __attribute__((address_space(1)))
#define AS3 __attribute__((address_space(3)))

typedef __bf16 bf16x8 __attribute__((ext_vector_type(8)));
typedef __bf16 bf16x4 __attribute__((ext_vector_type(4)));
typedef float  f32x4  __attribute__((ext_vector_type(4)));

// Per-batch element strides
#define XB_STRIDE   4194304ul   // 4096*1024 bf16 (also Qb, Kb, Vt, input-slice fp32)
#define SC_STRIDE   16777216ul  // 4096*4096 fp32
#define P_STRIDE    33554432ul  // score batch stride in bf16 units
#define OUT_STRIDE  8388608ul   // 2048*4096 fp32

// ---------------------------------------------------------------------------
// Copy input [B][1024][4096] fp32 into top half of out [B][2048][4096]
__global__ void copy_in_k(const float4* __restrict__ in, float4* __restrict__ out) {
  int i = blockIdx.x * 256 + threadIdx.x;       // 4*1024*4096/4 = 4194304
  int b = i >> 20;
  int r = i & 1048575;
  out[(long)b * 2097152 + r] = in[i];
}

// input slice [1024][4096] fp32 -> xb [4096][1024] bf16 (tiled transpose), batched z
__global__ void transpose_x_k(const float* __restrict__ in, __bf16* __restrict__ out) {
  in  += (size_t)blockIdx.z * XB_STRIDE;
  out += (size_t)blockIdx.z * XB_STRIDE;
  __shared__ float t[32][33];
  int s0 = blockIdx.x * 32, c0 = blockIdx.y * 32;
  int tx = threadIdx.x, ty = threadIdx.y;
#pragma unroll
  for (int i = 0; i < 4; i++)
    t[ty + i * 8][tx] = in[(c0 + ty + i * 8) * 4096 + s0 + tx];
  __syncthreads();
#pragma unroll
  for (int i = 0; i < 4; i++)
    out[(s0 + ty + i * 8) * 1024 + c0 + tx] = (__bf16)t[tx][ty + i * 8];
}

// Wq/Wk/Wv [1024][1024] fp32 -> Wt [3072][1024] bf16 transposed, Q slice pre-scaled 1/32
__global__ void transpose_w_k(const float* __restrict__ Wq, const float* __restrict__ Wk,
                              const float* __restrict__ Wv, __bf16* __restrict__ Wt) {
  __shared__ float t[32][33];
  int sel = blockIdx.z;
  const float* W = sel == 0 ? Wq : (sel == 1 ? Wk : Wv);
  float scale = sel == 0 ? 0.03125f : 1.0f;
  int n0 = blockIdx.x * 32, c0 = blockIdx.y * 32;
  int tx = threadIdx.x, ty = threadIdx.y;
#pragma unroll
  for (int i = 0; i < 4; i++)
    t[ty + i * 8][tx] = W[(c0 + ty + i * 8) * 1024 + n0 + tx];
  __syncthreads();
#pragma unroll
  for (int i = 0; i < 4; i++)
    Wt[(sel * 1024 + n0 + ty + i * 8) * 1024 + c0 + tx] = (__bf16)(t[tx][ty + i * 8] * scale);
}

__global__ void bcat_k(const float* __restrict__ bq, const float* __restrict__ bk,
                       const float* __restrict__ bv, float* __restrict__ bcat) {
  int n = blockIdx.x * 256 + threadIdx.x;       // 3072 total
  float v = n < 1024 ? bq[n] * 0.03125f : (n < 2048 ? bk[n - 1024] : bv[n - 2048]);
  bcat[n] = v;
}

// ---------------------------------------------------------------------------
// 128x128 bf16 MFMA GEMM core (m97 structure): 256 threads = 4 waves in 2x2,
// each wave 4x4 fragments of 16x16x32. A row-major [M][K], B^T row-major [N][K].
// ---------------------------------------------------------------------------
__device__ __forceinline__ void gemm128_core(const __bf16* __restrict__ A, int lda, int m0,
                                             const __bf16* __restrict__ B, int ldb, int n0,
                                             int kbeg, int kend, __bf16* As, __bf16* Bs,
                                             f32x4 acc[4][4]) {
  const int tid = threadIdx.x;
  const int lane = tid & 63;
  const int wid = tid >> 6;
  const int wr = wid >> 1, wc = wid & 1;
  const int lr = lane & 15;
  const int lk = (lane >> 4) << 3;
  const int srow = tid >> 2;            // 0..63
  const int skq = (tid & 3) << 3;       // 0,8,16,24
  const __bf16* ga = A + (long)(m0 + srow) * lda + skq;
  const __bf16* gb = B + (long)(n0 + srow) * ldb + skq;

  for (int k0 = kbeg; k0 < kend; k0 += 32) {
    __builtin_amdgcn_global_load_lds((const AS1 void*)(ga + k0),            (AS3 void*)(As + tid * 8),        16, 0, 0);
    __builtin_amdgcn_global_load_lds((const AS1 void*)(ga + k0 + 64 * lda), (AS3 void*)(As + tid * 8 + 2048), 16, 0, 0);
    __builtin_amdgcn_global_load_lds((const AS1 void*)(gb + k0),            (AS3 void*)(Bs + tid * 8),        16, 0, 0);
    __builtin_amdgcn_global_load_lds((const AS1 void*)(gb + k0 + 64 * ldb), (AS3 void*)(Bs + tid * 8 + 2048), 16, 0, 0);
    __syncthreads();
    bf16x8 af[4], bfr[4];
#pragma unroll
    for (int m = 0; m < 4; m++)
      af[m] = *(const bf16x8*)(As + (wr * 64 + m * 16 + lr) * 32 + lk);
#pragma unroll
    for (int n = 0; n < 4; n++)
      bfr[n] = *(const bf16x8*)(Bs + (wc * 64 + n * 16 + lr) * 32 + lk);
#pragma unroll
    for (int m = 0; m < 4; m++)
#pragma unroll
      for (int n = 0; n < 4; n++)
        acc[m][n] = __builtin_amdgcn_mfma_f32_16x16x32_bf16(af[m], bfr[n], acc[m][n], 0, 0, 0);
    __syncthreads();
  }
}

// ---------------------------------------------------------------------------
// QKV fused projection (batched z): [4096 x 3072] = xb[4096x1024] @ Wt^T
__global__ void qkv_gemm_k(const __bf16* __restrict__ xb, const __bf16* __restrict__ Wt,
                           const float* __restrict__ bcat, __bf16* __restrict__ Qb,
                           __bf16* __restrict__ Kb, __bf16* __restrict__ Vt) {
  size_t zo = (size_t)blockIdx.z * XB_STRIDE;
  xb += zo; Qb += zo; Kb += zo; Vt += zo;
  __shared__ __bf16 As[4096], Bs[4096];
  f32x4 acc[4][4] = {};
  int m0 = blockIdx.y * 128, n0 = blockIdx.x * 128;
  gemm128_core(xb, 1024, m0, Wt, 1024, n0, 0, 1024, As, Bs, acc);

  const int lane = threadIdx.x & 63;
  const int wid = threadIdx.x >> 6;
  const int wr = wid >> 1, wc = wid & 1;
  const int lr = lane & 15;
  const int lg = (lane >> 4) * 4;
#pragma unroll
  for (int m = 0; m < 4; m++) {
    int rs = m0 + wr * 64 + m * 16 + lg;
#pragma unroll
    for (int n = 0; n < 4; n++) {
      int col = n0 + wc * 64 + n * 16 + lr;
      float bias = bcat[col];
      if (col < 1024) {
#pragma unroll
        for (int r = 0; r < 4; r++)
          Qb[(rs + r) * 1024 + col] = (__bf16)(acc[m][n][r] + bias);
      } else if (col < 2048) {
#pragma unroll
        for (int r = 0; r < 4; r++)
          Kb[(rs + r) * 1024 + (col - 1024)] = (__bf16)(acc[m][n][r] + bias);
      } else {
        bf16x4 t4;
#pragma unroll
        for (int r = 0; r < 4; r++) t4[r] = (__bf16)(acc[m][n][r] + bias);
        *(bf16x4*)(Vt + (long)(col - 2048) * 4096 + rs) = t4;
      }
    }
  }
}

// ---------------------------------------------------------------------------
// QK^T (batched z): scores[s][t] = Q[s,:]·K[t,:]. Upper-tri tiles skipped.
__global__ void qk_gemm_k(const __bf16* __restrict__ Qb, const __bf16* __restrict__ Kb,
                          float* __restrict__ sc) {
  if (blockIdx.x > blockIdx.y) return;
  size_t zo = (size_t)blockIdx.z * XB_STRIDE;
  Qb += zo; Kb += zo;
  sc += (size_t)blockIdx.z * SC_STRIDE;
  __shared__ __bf16 As[4096], Bs[4096];
  f32x4 acc[4][4] = {};
  int m0 = blockIdx.y * 128, n0 = blockIdx.x * 128;
  gemm128_core(Qb, 1024, m0, Kb, 1024, n0, 0, 1024, As, Bs, acc);

  const int lane = threadIdx.x & 63;
  const int wid = threadIdx.x >> 6;
  const int wr = wid >> 1, wc = wid & 1;
  const int lr = lane & 15;
  const int lg = (lane >> 4) * 4;
#pragma unroll
  for (int m = 0; m < 4; m++) {
    int rs = m0 + wr * 64 + m * 16 + lg;
#pragma unroll
    for (int n = 0; n < 4; n++) {
      int col = n0 + wc * 64 + n * 16 + lr;
#pragma unroll
      for (int r = 0; r < 4; r++)
        sc[(long)(rs + r) * 4096 + col] = acc[m][n][r];
    }
  }
}

// ---------------------------------------------------------------------------
// Row softmax, causal + alibi (batched: blockIdx.y). P bf16 written in place
// into the second 8KB half of each 16KB score row, only up to the causal tile
// bound round_up(s+1,128) that pv_gemm reads.
__global__ void softmax_k(float* __restrict__ sc, const float* __restrict__ frame,
                          const float* __restrict__ alibi_p) {
  sc += (size_t)blockIdx.y * SC_STRIDE;
  __shared__ float buf[4096];
  __shared__ float red[4];
  int s = blockIdx.x;
  float* srow = sc + (long)s * 4096;
  __bf16* prow = (__bf16*)(srow + 2048);
  int tid = threadIdx.x, lane = tid & 63, wid = tid >> 6;
  float sig = 1.0f / (1.0f + __expf(-alibi_p[0]));
  float fs = frame[s];
  int n = s + 1;
  int bound = ((s >> 7) + 1) << 7;    // what pv reads

  float mx = -3.4e38f;
  for (int t = tid; t < n; t += 256) {
    float v = srow[t] - sig * fabsf(frame[t] - fs);
    buf[t] = v;
    mx = fmaxf(mx, v);
  }
#pragma unroll
  for (int o = 32; o; o >>= 1) mx = fmaxf(mx, __shfl_xor(mx, o, 64));
  if (lane == 0) red[wid] = mx;
  __syncthreads();
  mx = fmaxf(fmaxf(red[0], red[1]), fmaxf(red[2], red[3]));

  float sum = 0.0f;
  for (int t = tid; t < n; t += 256) {
    float e = __expf(buf[t] - mx);
    buf[t] = e;
    sum += e;
  }
#pragma unroll
  for (int o = 32; o; o >>= 1) sum += __shfl_xor(sum, o, 64);
  __syncthreads();
  if (lane == 0) red[wid] = sum;
  __syncthreads();
  sum = red[0] + red[1] + red[2] + red[3];
  float inv = 1.0f / sum;

  for (int t = tid; t < bound; t += 256) {
    float p = (t < n) ? buf[t] * inv : 0.0f;
    prow[t] = (__bf16)p;
  }
}

// ---------------------------------------------------------------------------
// PV (batched z): out[v][s] = sum_{t<=s} P[s,t] * Vt[v,t], direct float4 store
// into the transposed output slice. P row stride 8192 bf16 (16KB).
__global__ void pv_gemm_k(const __bf16* __restrict__ P, const __bf16* __restrict__ Vt,
                          float* __restrict__ outb) {
  P    += (size_t)blockIdx.z * P_STRIDE;
  Vt   += (size_t)blockIdx.z * XB_STRIDE;
  outb += (size_t)blockIdx.z * OUT_STRIDE;
  __shared__ __bf16 As[4096], Bs[4096];
  f32x4 acc[4][4] = {};
  int m0 = blockIdx.y * 128, n0 = blockIdx.x * 128;
  gemm128_core(P, 8192, m0, Vt, 4096, n0, 0, m0 + 128, As, Bs, acc);

  const int lane = threadIdx.x & 63;
  const int wid = threadIdx.x >> 6;
  const int wr = wid >> 1, wc = wid & 1;
  const int lr = lane & 15;
  const int lg = (lane >> 4) * 4;
#pragma unroll
  for (int m = 0; m < 4; m++) {
    int rs = m0 + wr * 64 + m * 16 + lg;
#pragma unroll
    for (int n = 0; n < 4; n++) {
      int col = n0 + wc * 64 + n * 16 + lr;   // v index
      *(f32x4*)(outb + (long)col * 4096 + rs) = acc[m][n];
    }
  }
}

// ---------------------------------------------------------------------------

static inline char* align256(char* p) {
  return (char*)(((uintptr_t)p + 255) & ~(uintptr_t)255);
}

extern "C" void kernel_launch(void* const* d_in, const int* in_sizes, int n_in,
                              void* d_out, int out_size, void* d_ws, size_t ws_size,
                              hipStream_t stream) {
  const float* input = (const float*)d_in[0];   // [4][1024][4096]
  const float* frame = (const float*)d_in[1];   // [4096]
  const float* Wq = (const float*)d_in[2];
  const float* bq = (const float*)d_in[3];
  const float* Wk = (const float*)d_in[4];
  const float* bk = (const float*)d_in[5];
  const float* Wv = (const float*)d_in[6];
  const float* bv = (const float*)d_in[7];
  const float* alibi = (const float*)d_in[8];
  float* out = (float*)d_out;                   // [4][2048][4096]

  // Batched (z=4) path needs: Wt 6MB + xb/Qb/Kb/Vt 4x8MB each + sc 4x67MB ~= 410MB
  const size_t NEED_BATCHED = (size_t)3072 * 1024 * 2 + 4096 +
                              4 * (4 * XB_STRIDE * 2) + 4 * SC_STRIDE * 4 + 2048;
  int NB = (ws_size >= NEED_BATCHED) ? 4 : 1;

  char* p = (char*)d_ws;
  __bf16* Wt = (__bf16*)p;  p += (size_t)3072 * 1024 * 2;
  float* bcat = (float*)p;  p += 3072 * 4;                    p = align256(p);
  __bf16* xb = (__bf16*)p;  p += NB * XB_STRIDE * 2;          p = align256(p);
  __bf16* Qb = (__bf16*)p;  p += NB * XB_STRIDE * 2;          p = align256(p);
  __bf16* Kb = (__bf16*)p;  p += NB * XB_STRIDE * 2;          p = align256(p);
  __bf16* Vt = (__bf16*)p;  p += NB * XB_STRIDE * 2;          p = align256(p);
  float* sc = (float*)p;    // NB x [4096][4096] fp32; P aliased into row halves

  transpose_w_k<<<dim3(32, 32, 3), dim3(32, 8), 0, stream>>>(Wq, Wk, Wv, Wt);
  bcat_k<<<12, 256, 0, stream>>>(bq, bk, bv, bcat);
  copy_in_k<<<16384, 256, 0, stream>>>((const float4*)input, (float4*)out);

  for (int b0 = 0; b0 < 4; b0 += NB) {
    const float* inb = input + (size_t)b0 * XB_STRIDE;
    float* outb = out + (size_t)b0 * OUT_STRIDE + (size_t)1024 * 4096;
    transpose_x_k<<<dim3(128, 32, NB), dim3(32, 8), 0, stream>>>(inb, xb);
    qkv_gemm_k<<<dim3(24, 32, NB), 256, 0, stream>>>(xb, Wt, bcat, Qb, Kb, Vt);
    qk_gemm_k<<<dim3(32, 32, NB), 256, 0, stream>>>(Qb, Kb, sc);
    softmax_k<<<dim3(4096, NB), 256, 0, stream>>>(sc, frame, alibi);
    pv_gemm_k<<<dim3(8, 32, NB), 256, 0, stream>>>((const __bf16*)((char*)sc + 8192), Vt, outb);
  }
}

// Round 4
// 545.110 us; speedup vs baseline: 1.8028x; 1.0350x over previous
//
#include <hip/hip_runtime.h>
#include <cstdint>

#define AS1 __attribute__((address_space(1)))
#define AS3 __attribute__((address_space(3)))

typedef __bf16 bf16x8 __attribute__((ext_vector_type(8)));
typedef __bf16 bf16x4 __attribute__((ext_vector_type(4)));
typedef float  f32x4  __attribute__((ext_vector_type(4)));

// Per-batch element strides
#define XB_STRIDE   4194304ul   // 4096*1024 bf16 (also Qb, Kb, Vt, input-slice fp32)
#define SC_STRIDE   16777216ul  // 4096*4096 fp32
#define P_STRIDE    33554432ul  // score batch stride in bf16 units
#define OUT_STRIDE  8388608ul   // 2048*4096 fp32

// ---------------------------------------------------------------------------
// Copy input [B][1024][4096] fp32 into top half of out [B][2048][4096]
__global__ void copy_in_k(const float4* __restrict__ in, float4* __restrict__ out) {
  int i = blockIdx.x * 256 + threadIdx.x;       // 4*1024*4096/4 = 4194304
  int b = i >> 20;
  int r = i & 1048575;
  out[(long)b * 2097152 + r] = in[i];
}

// input slice [1024][4096] fp32 -> xb [4096][1024] bf16 (tiled transpose), batched z
__global__ void transpose_x_k(const float* __restrict__ in, __bf16* __restrict__ out) {
  in  += (size_t)blockIdx.z * XB_STRIDE;
  out += (size_t)blockIdx.z * XB_STRIDE;
  __shared__ float t[32][33];
  int s0 = blockIdx.x * 32, c0 = blockIdx.y * 32;
  int tx = threadIdx.x, ty = threadIdx.y;
#pragma unroll
  for (int i = 0; i < 4; i++)
    t[ty + i * 8][tx] = in[(c0 + ty + i * 8) * 4096 + s0 + tx];
  __syncthreads();
#pragma unroll
  for (int i = 0; i < 4; i++)
    out[(s0 + ty + i * 8) * 1024 + c0 + tx] = (__bf16)t[tx][ty + i * 8];
}

// Wq/Wk/Wv [1024][1024] fp32 -> Wt [3072][1024] bf16 transposed, Q slice pre-scaled 1/32
__global__ void transpose_w_k(const float* __restrict__ Wq, const float* __restrict__ Wk,
                              const float* __restrict__ Wv, __bf16* __restrict__ Wt) {
  __shared__ float t[32][33];
  int sel = blockIdx.z;
  const float* W = sel == 0 ? Wq : (sel == 1 ? Wk : Wv);
  float scale = sel == 0 ? 0.03125f : 1.0f;
  int n0 = blockIdx.x * 32, c0 = blockIdx.y * 32;
  int tx = threadIdx.x, ty = threadIdx.y;
#pragma unroll
  for (int i = 0; i < 4; i++)
    t[ty + i * 8][tx] = W[(c0 + ty + i * 8) * 1024 + n0 + tx];
  __syncthreads();
#pragma unroll
  for (int i = 0; i < 4; i++)
    Wt[(sel * 1024 + n0 + ty + i * 8) * 1024 + c0 + tx] = (__bf16)(t[tx][ty + i * 8] * scale);
}

__global__ void bcat_k(const float* __restrict__ bq, const float* __restrict__ bk,
                       const float* __restrict__ bv, float* __restrict__ bcat) {
  int n = blockIdx.x * 256 + threadIdx.x;       // 3072 total
  float v = n < 1024 ? bq[n] * 0.03125f : (n < 2048 ? bk[n - 1024] : bv[n - 2048]);
  bcat[n] = v;
}

// ---------------------------------------------------------------------------
// 128x128 bf16 MFMA GEMM core (m97 structure): 256 threads = 4 waves in 2x2,
// each wave 4x4 fragments of 16x16x32. A row-major [M][K], B^T row-major [N][K].
// ---------------------------------------------------------------------------
__device__ __forceinline__ void gemm128_core(const __bf16* __restrict__ A, int lda, int m0,
                                             const __bf16* __restrict__ B, int ldb, int n0,
                                             int kbeg, int kend, __bf16* As, __bf16* Bs,
                                             f32x4 acc[4][4]) {
  const int tid = threadIdx.x;
  const int lane = tid & 63;
  const int wid = tid >> 6;
  const int wr = wid >> 1, wc = wid & 1;
  const int lr = lane & 15;
  const int lk = (lane >> 4) << 3;
  const int srow = tid >> 2;            // 0..63
  const int skq = (tid & 3) << 3;       // 0,8,16,24
  const __bf16* ga = A + (long)(m0 + srow) * lda + skq;
  const __bf16* gb = B + (long)(n0 + srow) * ldb + skq;

  for (int k0 = kbeg; k0 < kend; k0 += 32) {
    __builtin_amdgcn_global_load_lds((const AS1 void*)(ga + k0),            (AS3 void*)(As + tid * 8),        16, 0, 0);
    __builtin_amdgcn_global_load_lds((const AS1 void*)(ga + k0 + 64 * lda), (AS3 void*)(As + tid * 8 + 2048), 16, 0, 0);
    __builtin_amdgcn_global_load_lds((const AS1 void*)(gb + k0),            (AS3 void*)(Bs + tid * 8),        16, 0, 0);
    __builtin_amdgcn_global_load_lds((const AS1 void*)(gb + k0 + 64 * ldb), (AS3 void*)(Bs + tid * 8 + 2048), 16, 0, 0);
    __syncthreads();
    bf16x8 af[4], bfr[4];
#pragma unroll
    for (int m = 0; m < 4; m++)
      af[m] = *(const bf16x8*)(As + (wr * 64 + m * 16 + lr) * 32 + lk);
#pragma unroll
    for (int n = 0; n < 4; n++)
      bfr[n] = *(const bf16x8*)(Bs + (wc * 64 + n * 16 + lr) * 32 + lk);
#pragma unroll
    for (int m = 0; m < 4; m++)
#pragma unroll
      for (int n = 0; n < 4; n++)
        acc[m][n] = __builtin_amdgcn_mfma_f32_16x16x32_bf16(af[m], bfr[n], acc[m][n], 0, 0, 0);
    __syncthreads();
  }
}

// ---------------------------------------------------------------------------
// QKV fused projection (batched z): [4096 x 3072] = xb[4096x1024] @ Wt^T
__global__ void qkv_gemm_k(const __bf16* __restrict__ xb, const __bf16* __restrict__ Wt,
                           const float* __restrict__ bcat, __bf16* __restrict__ Qb,
                           __bf16* __restrict__ Kb, __bf16* __restrict__ Vt) {
  size_t zo = (size_t)blockIdx.z * XB_STRIDE;
  xb += zo; Qb += zo; Kb += zo; Vt += zo;
  __shared__ __bf16 As[4096], Bs[4096];
  f32x4 acc[4][4] = {};
  int m0 = blockIdx.y * 128, n0 = blockIdx.x * 128;
  gemm128_core(xb, 1024, m0, Wt, 1024, n0, 0, 1024, As, Bs, acc);

  const int lane = threadIdx.x & 63;
  const int wid = threadIdx.x >> 6;
  const int wr = wid >> 1, wc = wid & 1;
  const int lr = lane & 15;
  const int lg = (lane >> 4) * 4;
#pragma unroll
  for (int m = 0; m < 4; m++) {
    int rs = m0 + wr * 64 + m * 16 + lg;
#pragma unroll
    for (int n = 0; n < 4; n++) {
      int col = n0 + wc * 64 + n * 16 + lr;
      float bias = bcat[col];
      if (col < 1024) {
#pragma unroll
        for (int r = 0; r < 4; r++)
          Qb[(rs + r) * 1024 + col] = (__bf16)(acc[m][n][r] + bias);
      } else if (col < 2048) {
#pragma unroll
        for (int r = 0; r < 4; r++)
          Kb[(rs + r) * 1024 + (col - 1024)] = (__bf16)(acc[m][n][r] + bias);
      } else {
        bf16x4 t4;
#pragma unroll
        for (int r = 0; r < 4; r++) t4[r] = (__bf16)(acc[m][n][r] + bias);
        *(bf16x4*)(Vt + (long)(col - 2048) * 4096 + rs) = t4;
      }
    }
  }
}

// ---------------------------------------------------------------------------
// QK^T (batched z): scores[s][t] = Q[s,:]·K[t,:]. Upper-tri tiles skipped.
__global__ void qk_gemm_k(const __bf16* __restrict__ Qb, const __bf16* __restrict__ Kb,
                          float* __restrict__ sc) {
  if (blockIdx.x > blockIdx.y) return;
  size_t zo = (size_t)blockIdx.z * XB_STRIDE;
  Qb += zo; Kb += zo;
  sc += (size_t)blockIdx.z * SC_STRIDE;
  __shared__ __bf16 As[4096], Bs[4096];
  f32x4 acc[4][4] = {};
  int m0 = blockIdx.y * 128, n0 = blockIdx.x * 128;
  gemm128_core(Qb, 1024, m0, Kb, 1024, n0, 0, 1024, As, Bs, acc);

  const int lane = threadIdx.x & 63;
  const int wid = threadIdx.x >> 6;
  const int wr = wid >> 1, wc = wid & 1;
  const int lr = lane & 15;
  const int lg = (lane >> 4) * 4;
#pragma unroll
  for (int m = 0; m < 4; m++) {
    int rs = m0 + wr * 64 + m * 16 + lg;
#pragma unroll
    for (int n = 0; n < 4; n++) {
      int col = n0 + wc * 64 + n * 16 + lr;
#pragma unroll
      for (int r = 0; r < 4; r++)
        sc[(long)(rs + r) * 4096 + col] = acc[m][n][r];
    }
  }
}

// ---------------------------------------------------------------------------
// Row softmax, causal + alibi (batched: blockIdx.y). All row state lives in
// registers: each thread owns <=4 float4 chunks (statically indexed). P bf16
// is written in place into the second 8KB half of each 16KB score row, up to
// the causal tile bound round_up(s+1,128) that pv_gemm reads.
__global__ void softmax_k(float* __restrict__ sc, const float* __restrict__ frame,
                          const float* __restrict__ alibi_p) {
  sc += (size_t)blockIdx.y * SC_STRIDE;
  __shared__ float red[4];
  int s = blockIdx.x;
  float* srow = sc + (long)s * 4096;
  __bf16* prow = (__bf16*)(srow + 2048);
  int tid = threadIdx.x, lane = tid & 63, wid = tid >> 6;
  float sig = 1.0f / (1.0f + __expf(-alibi_p[0]));
  float fs = frame[s];
  int n = s + 1;
  int bound = ((s >> 7) + 1) << 7;     // multiple of 128; == kend read by pv
  int nv = (n + 3) >> 2;               // float4 chunks covering [0, n)
  int bv = bound >> 2;

  const float4* srow4 = (const float4*)srow;
  const float4* fr4 = (const float4*)frame;
  float4 vals[4];

  float mx = -3.4e38f;
#pragma unroll
  for (int it = 0; it < 4; it++) {
    int i = tid + it * 256;
    if (i < nv) {
      float4 v = srow4[i];
      float4 f = fr4[i];
      int t0 = i << 2;
      float a0 = (t0     < n) ? v.x - sig * fabsf(f.x - fs) : -3.4e38f;
      float a1 = (t0 + 1 < n) ? v.y - sig * fabsf(f.y - fs) : -3.4e38f;
      float a2 = (t0 + 2 < n) ? v.z - sig * fabsf(f.z - fs) : -3.4e38f;
      float a3 = (t0 + 3 < n) ? v.w - sig * fabsf(f.w - fs) : -3.4e38f;
      vals[it] = make_float4(a0, a1, a2, a3);
      mx = fmaxf(fmaxf(fmaxf(mx, a0), fmaxf(a1, a2)), a3);
    }
  }
#pragma unroll
  for (int o = 32; o; o >>= 1) mx = fmaxf(mx, __shfl_xor(mx, o, 64));
  if (lane == 0) red[wid] = mx;
  __syncthreads();
  mx = fmaxf(fmaxf(red[0], red[1]), fmaxf(red[2], red[3]));

  float sum = 0.0f;
#pragma unroll
  for (int it = 0; it < 4; it++) {
    int i = tid + it * 256;
    if (i < nv) {
      float4 v = vals[it];
      float e0 = __expf(v.x - mx), e1 = __expf(v.y - mx);
      float e2 = __expf(v.z - mx), e3 = __expf(v.w - mx);
      vals[it] = make_float4(e0, e1, e2, e3);
      sum += (e0 + e1) + (e2 + e3);
    }
  }
#pragma unroll
  for (int o = 32; o; o >>= 1) sum += __shfl_xor(sum, o, 64);
  __syncthreads();
  if (lane == 0) red[wid] = sum;
  __syncthreads();
  sum = red[0] + red[1] + red[2] + red[3];
  float inv = 1.0f / sum;

#pragma unroll
  for (int it = 0; it < 4; it++) {
    int i = tid + it * 256;
    if (i < bv) {
      bf16x4 o;
      if (i < nv) {
        float4 v = vals[it];
        o[0] = (__bf16)(v.x * inv); o[1] = (__bf16)(v.y * inv);
        o[2] = (__bf16)(v.z * inv); o[3] = (__bf16)(v.w * inv);
      } else {
        o[0] = o[1] = o[2] = o[3] = (__bf16)0.0f;
      }
      *(bf16x4*)(prow + (i << 2)) = o;
    }
  }
}

// ---------------------------------------------------------------------------
// PV (batched z): out[v][s] = sum_{t<=s} P[s,t] * Vt[v,t], direct float4 store
// into the transposed output slice. P row stride 8192 bf16 (16KB).
// Heavy-first (LPT): blockIdx.y=0 -> deepest m-tile so long blocks start early.
__global__ void pv_gemm_k(const __bf16* __restrict__ P, const __bf16* __restrict__ Vt,
                          float* __restrict__ outb) {
  P    += (size_t)blockIdx.z * P_STRIDE;
  Vt   += (size_t)blockIdx.z * XB_STRIDE;
  outb += (size_t)blockIdx.z * OUT_STRIDE;
  __shared__ __bf16 As[4096], Bs[4096];
  f32x4 acc[4][4] = {};
  int mi = 31 - blockIdx.y;           // heavy-first dispatch order
  int m0 = mi * 128, n0 = blockIdx.x * 128;
  gemm128_core(P, 8192, m0, Vt, 4096, n0, 0, m0 + 128, As, Bs, acc);

  const int lane = threadIdx.x & 63;
  const int wid = threadIdx.x >> 6;
  const int wr = wid >> 1, wc = wid & 1;
  const int lr = lane & 15;
  const int lg = (lane >> 4) * 4;
#pragma unroll
  for (int m = 0; m < 4; m++) {
    int rs = m0 + wr * 64 + m * 16 + lg;
#pragma unroll
    for (int n = 0; n < 4; n++) {
      int col = n0 + wc * 64 + n * 16 + lr;   // v index
      *(f32x4*)(outb + (long)col * 4096 + rs) = acc[m][n];
    }
  }
}

// ---------------------------------------------------------------------------

static inline char* align256(char* p) {
  return (char*)(((uintptr_t)p + 255) & ~(uintptr_t)255);
}

extern "C" void kernel_launch(void* const* d_in, const int* in_sizes, int n_in,
                              void* d_out, int out_size, void* d_ws, size_t ws_size,
                              hipStream_t stream) {
  const float* input = (const float*)d_in[0];   // [4][1024][4096]
  const float* frame = (const float*)d_in[1];   // [4096]
  const float* Wq = (const float*)d_in[2];
  const float* bq = (const float*)d_in[3];
  const float* Wk = (const float*)d_in[4];
  const float* bk = (const float*)d_in[5];
  const float* Wv = (const float*)d_in[6];
  const float* bv = (const float*)d_in[7];
  const float* alibi = (const float*)d_in[8];
  float* out = (float*)d_out;                   // [4][2048][4096]

  // Batched (z=4) path needs: Wt 6MB + xb/Qb/Kb/Vt 4x8MB each + sc 4x67MB ~= 410MB
  const size_t NEED_BATCHED = (size_t)3072 * 1024 * 2 + 4096 +
                              4 * (4 * XB_STRIDE * 2) + 4 * SC_STRIDE * 4 + 2048;
  int NB = (ws_size >= NEED_BATCHED) ? 4 : 1;

  char* p = (char*)d_ws;
  __bf16* Wt = (__bf16*)p;  p += (size_t)3072 * 1024 * 2;
  float* bcat = (float*)p;  p += 3072 * 4;                    p = align256(p);
  __bf16* xb = (__bf16*)p;  p += NB * XB_STRIDE * 2;          p = align256(p);
  __bf16* Qb = (__bf16*)p;  p += NB * XB_STRIDE * 2;          p = align256(p);
  __bf16* Kb = (__bf16*)p;  p += NB * XB_STRIDE * 2;          p = align256(p);
  __bf16* Vt = (__bf16*)p;  p += NB * XB_STRIDE * 2;          p = align256(p);
  float* sc = (float*)p;    // NB x [4096][4096] fp32; P aliased into row halves

  transpose_w_k<<<dim3(32, 32, 3), dim3(32, 8), 0, stream>>>(Wq, Wk, Wv, Wt);
  bcat_k<<<12, 256, 0, stream>>>(bq, bk, bv, bcat);
  copy_in_k<<<16384, 256, 0, stream>>>((const float4*)input, (float4*)out);

  for (int b0 = 0; b0 < 4; b0 += NB) {
    const float* inb = input + (size_t)b0 * XB_STRIDE;
    float* outb = out + (size_t)b0 * OUT_STRIDE + (size_t)1024 * 4096;
    transpose_x_k<<<dim3(128, 32, NB), dim3(32, 8), 0, stream>>>(inb, xb);
    qkv_gemm_k<<<dim3(24, 32, NB), 256, 0, stream>>>(xb, Wt, bcat, Qb, Kb, Vt);
    qk_gemm_k<<<dim3(32, 32, NB), 256, 0, stream>>>(Qb, Kb, sc);
    softmax_k<<<dim3(4096, NB), 256, 0, stream>>>(sc, frame, alibi);
    pv_gemm_k<<<dim3(8, 32, NB), 256, 0, stream>>>((const __bf16*)((char*)sc + 8192), Vt, outb);
  }
}

// Round 5
// 503.561 us; speedup vs baseline: 1.9516x; 1.0825x over previous
//
#include <hip/hip_runtime.h>
#include <cstdint>

#define AS1 __attribute__((address_space(1)))
#define AS3 __attribute__((address_space(3)))

typedef __bf16 bf16x8 __attribute__((ext_vector_type(8)));
typedef __bf16 bf16x4 __attribute__((ext_vector_type(4)));
typedef float  f32x4  __attribute__((ext_vector_type(4)));

// Per-batch element strides
#define XB_STRIDE   4194304ul   // 4096*1024 bf16 (also Qb, Kb, Vt, input-slice fp32)
#define SC_STRIDE   16777216ul  // 4096*4096 fp32
#define P_STRIDE    33554432ul  // score batch stride in bf16 units
#define OUT_STRIDE  8388608ul   // 2048*4096 fp32

// ---------------------------------------------------------------------------
// Copy input [B][1024][4096] fp32 into top half of out [B][2048][4096]
__global__ void copy_in_k(const float4* __restrict__ in, float4* __restrict__ out) {
  int i = blockIdx.x * 256 + threadIdx.x;       // 4*1024*4096/4 = 4194304
  int b = i >> 20;
  int r = i & 1048575;
  out[(long)b * 2097152 + r] = in[i];
}

// input slice [1024][4096] fp32 -> xb [4096][1024] bf16 (tiled transpose), batched z
__global__ void transpose_x_k(const float* __restrict__ in, __bf16* __restrict__ out) {
  in  += (size_t)blockIdx.z * XB_STRIDE;
  out += (size_t)blockIdx.z * XB_STRIDE;
  __shared__ float t[32][33];
  int s0 = blockIdx.x * 32, c0 = blockIdx.y * 32;
  int tx = threadIdx.x, ty = threadIdx.y;
#pragma unroll
  for (int i = 0; i < 4; i++)
    t[ty + i * 8][tx] = in[(c0 + ty + i * 8) * 4096 + s0 + tx];
  __syncthreads();
#pragma unroll
  for (int i = 0; i < 4; i++)
    out[(s0 + ty + i * 8) * 1024 + c0 + tx] = (__bf16)t[tx][ty + i * 8];
}

// Wq/Wk/Wv [1024][1024] fp32 -> Wt [3072][1024] bf16 transposed, Q slice pre-scaled 1/32
__global__ void transpose_w_k(const float* __restrict__ Wq, const float* __restrict__ Wk,
                              const float* __restrict__ Wv, __bf16* __restrict__ Wt) {
  __shared__ float t[32][33];
  int sel = blockIdx.z;
  const float* W = sel == 0 ? Wq : (sel == 1 ? Wk : Wv);
  float scale = sel == 0 ? 0.03125f : 1.0f;
  int n0 = blockIdx.x * 32, c0 = blockIdx.y * 32;
  int tx = threadIdx.x, ty = threadIdx.y;
#pragma unroll
  for (int i = 0; i < 4; i++)
    t[ty + i * 8][tx] = W[(c0 + ty + i * 8) * 1024 + n0 + tx];
  __syncthreads();
#pragma unroll
  for (int i = 0; i < 4; i++)
    Wt[(sel * 1024 + n0 + ty + i * 8) * 1024 + c0 + tx] = (__bf16)(t[tx][ty + i * 8] * scale);
}

__global__ void bcat_k(const float* __restrict__ bq, const float* __restrict__ bk,
                       const float* __restrict__ bv, float* __restrict__ bcat) {
  int n = blockIdx.x * 256 + threadIdx.x;       // 3072 total
  float v = n < 1024 ? bq[n] * 0.03125f : (n < 2048 ? bk[n - 1024] : bv[n - 2048]);
  bcat[n] = v;
}

// ---------------------------------------------------------------------------
// 128x128 bf16 MFMA GEMM core (m97 structure): 256 threads = 4 waves in 2x2,
// each wave 4x4 fragments of 16x16x32. A row-major [M][K], B^T row-major [N][K].
// ---------------------------------------------------------------------------
__device__ __forceinline__ void gemm128_core(const __bf16* __restrict__ A, int lda, int m0,
                                             const __bf16* __restrict__ B, int ldb, int n0,
                                             int kbeg, int kend, __bf16* As, __bf16* Bs,
                                             f32x4 acc[4][4]) {
  const int tid = threadIdx.x;
  const int lane = tid & 63;
  const int wid = tid >> 6;
  const int wr = wid >> 1, wc = wid & 1;
  const int lr = lane & 15;
  const int lk = (lane >> 4) << 3;
  const int srow = tid >> 2;            // 0..63
  const int skq = (tid & 3) << 3;       // 0,8,16,24
  const __bf16* ga = A + (long)(m0 + srow) * lda + skq;
  const __bf16* gb = B + (long)(n0 + srow) * ldb + skq;

  for (int k0 = kbeg; k0 < kend; k0 += 32) {
    __builtin_amdgcn_global_load_lds((const AS1 void*)(ga + k0),            (AS3 void*)(As + tid * 8),        16, 0, 0);
    __builtin_amdgcn_global_load_lds((const AS1 void*)(ga + k0 + 64 * lda), (AS3 void*)(As + tid * 8 + 2048), 16, 0, 0);
    __builtin_amdgcn_global_load_lds((const AS1 void*)(gb + k0),            (AS3 void*)(Bs + tid * 8),        16, 0, 0);
    __builtin_amdgcn_global_load_lds((const AS1 void*)(gb + k0 + 64 * ldb), (AS3 void*)(Bs + tid * 8 + 2048), 16, 0, 0);
    __syncthreads();
    bf16x8 af[4], bfr[4];
#pragma unroll
    for (int m = 0; m < 4; m++)
      af[m] = *(const bf16x8*)(As + (wr * 64 + m * 16 + lr) * 32 + lk);
#pragma unroll
    for (int n = 0; n < 4; n++)
      bfr[n] = *(const bf16x8*)(Bs + (wc * 64 + n * 16 + lr) * 32 + lk);
#pragma unroll
    for (int m = 0; m < 4; m++)
#pragma unroll
      for (int n = 0; n < 4; n++)
        acc[m][n] = __builtin_amdgcn_mfma_f32_16x16x32_bf16(af[m], bfr[n], acc[m][n], 0, 0, 0);
    __syncthreads();
  }
}

// ---------------------------------------------------------------------------
// QKV fused projection (batched z): [4096 x 3072] = xb[4096x1024] @ Wt^T
__global__ void qkv_gemm_k(const __bf16* __restrict__ xb, const __bf16* __restrict__ Wt,
                           const float* __restrict__ bcat, __bf16* __restrict__ Qb,
                           __bf16* __restrict__ Kb, __bf16* __restrict__ Vt) {
  size_t zo = (size_t)blockIdx.z * XB_STRIDE;
  xb += zo; Qb += zo; Kb += zo; Vt += zo;
  __shared__ __bf16 As[4096], Bs[4096];
  f32x4 acc[4][4] = {};
  int m0 = blockIdx.y * 128, n0 = blockIdx.x * 128;
  gemm128_core(xb, 1024, m0, Wt, 1024, n0, 0, 1024, As, Bs, acc);

  const int lane = threadIdx.x & 63;
  const int wid = threadIdx.x >> 6;
  const int wr = wid >> 1, wc = wid & 1;
  const int lr = lane & 15;
  const int lg = (lane >> 4) * 4;
#pragma unroll
  for (int m = 0; m < 4; m++) {
    int rs = m0 + wr * 64 + m * 16 + lg;
#pragma unroll
    for (int n = 0; n < 4; n++) {
      int col = n0 + wc * 64 + n * 16 + lr;
      float bias = bcat[col];
      if (col < 1024) {
#pragma unroll
        for (int r = 0; r < 4; r++)
          Qb[(rs + r) * 1024 + col] = (__bf16)(acc[m][n][r] + bias);
      } else if (col < 2048) {
#pragma unroll
        for (int r = 0; r < 4; r++)
          Kb[(rs + r) * 1024 + (col - 1024)] = (__bf16)(acc[m][n][r] + bias);
      } else {
        bf16x4 t4;
#pragma unroll
        for (int r = 0; r < 4; r++) t4[r] = (__bf16)(acc[m][n][r] + bias);
        *(bf16x4*)(Vt + (long)(col - 2048) * 4096 + rs) = t4;
      }
    }
  }
}

// ---------------------------------------------------------------------------
// QK^T (batched z): scores[s][t] = Q[s,:]·K[t,:]. Upper-tri tiles skipped.
__global__ void qk_gemm_k(const __bf16* __restrict__ Qb, const __bf16* __restrict__ Kb,
                          float* __restrict__ sc) {
  if (blockIdx.x > blockIdx.y) return;
  size_t zo = (size_t)blockIdx.z * XB_STRIDE;
  Qb += zo; Kb += zo;
  sc += (size_t)blockIdx.z * SC_STRIDE;
  __shared__ __bf16 As[4096], Bs[4096];
  f32x4 acc[4][4] = {};
  int m0 = blockIdx.y * 128, n0 = blockIdx.x * 128;
  gemm128_core(Qb, 1024, m0, Kb, 1024, n0, 0, 1024, As, Bs, acc);

  const int lane = threadIdx.x & 63;
  const int wid = threadIdx.x >> 6;
  const int wr = wid >> 1, wc = wid & 1;
  const int lr = lane & 15;
  const int lg = (lane >> 4) * 4;
#pragma unroll
  for (int m = 0; m < 4; m++) {
    int rs = m0 + wr * 64 + m * 16 + lg;
#pragma unroll
    for (int n = 0; n < 4; n++) {
      int col = n0 + wc * 64 + n * 16 + lr;
#pragma unroll
      for (int r = 0; r < 4; r++)
        sc[(long)(rs + r) * 4096 + col] = acc[m][n][r];
    }
  }
}

// ---------------------------------------------------------------------------
// Row softmax, causal + alibi (batched: blockIdx.y). All row state lives in
// registers: each thread owns <=4 float4 chunks (statically indexed). P bf16
// is written in place into the second 8KB half of each 16KB score row, up to
// the causal tile bound round_up(s+1,128) that pv_gemm reads.
__global__ void softmax_k(float* __restrict__ sc, const float* __restrict__ frame,
                          const float* __restrict__ alibi_p) {
  sc += (size_t)blockIdx.y * SC_STRIDE;
  __shared__ float red[4];
  int s = blockIdx.x;
  float* srow = sc + (long)s * 4096;
  __bf16* prow = (__bf16*)(srow + 2048);
  int tid = threadIdx.x, lane = tid & 63, wid = tid >> 6;
  float sig = 1.0f / (1.0f + __expf(-alibi_p[0]));
  float fs = frame[s];
  int n = s + 1;
  int bound = ((s >> 7) + 1) << 7;     // multiple of 128; == kend read by pv
  int nv = (n + 3) >> 2;               // float4 chunks covering [0, n)
  int bv = bound >> 2;

  const float4* srow4 = (const float4*)srow;
  const float4* fr4 = (const float4*)frame;
  float4 vals[4];

  float mx = -3.4e38f;
#pragma unroll
  for (int it = 0; it < 4; it++) {
    int i = tid + it * 256;
    if (i < nv) {
      float4 v = srow4[i];
      float4 f = fr4[i];
      int t0 = i << 2;
      float a0 = (t0     < n) ? v.x - sig * fabsf(f.x - fs) : -3.4e38f;
      float a1 = (t0 + 1 < n) ? v.y - sig * fabsf(f.y - fs) : -3.4e38f;
      float a2 = (t0 + 2 < n) ? v.z - sig * fabsf(f.z - fs) : -3.4e38f;
      float a3 = (t0 + 3 < n) ? v.w - sig * fabsf(f.w - fs) : -3.4e38f;
      vals[it] = make_float4(a0, a1, a2, a3);
      mx = fmaxf(fmaxf(fmaxf(mx, a0), fmaxf(a1, a2)), a3);
    }
  }
#pragma unroll
  for (int o = 32; o; o >>= 1) mx = fmaxf(mx, __shfl_xor(mx, o, 64));
  if (lane == 0) red[wid] = mx;
  __syncthreads();
  mx = fmaxf(fmaxf(red[0], red[1]), fmaxf(red[2], red[3]));

  float sum = 0.0f;
#pragma unroll
  for (int it = 0; it < 4; it++) {
    int i = tid + it * 256;
    if (i < nv) {
      float4 v = vals[it];
      float e0 = __expf(v.x - mx), e1 = __expf(v.y - mx);
      float e2 = __expf(v.z - mx), e3 = __expf(v.w - mx);
      vals[it] = make_float4(e0, e1, e2, e3);
      sum += (e0 + e1) + (e2 + e3);
    }
  }
#pragma unroll
  for (int o = 32; o; o >>= 1) sum += __shfl_xor(sum, o, 64);
  __syncthreads();
  if (lane == 0) red[wid] = sum;
  __syncthreads();
  sum = red[0] + red[1] + red[2] + red[3];
  float inv = 1.0f / sum;

#pragma unroll
  for (int it = 0; it < 4; it++) {
    int i = tid + it * 256;
    if (i < bv) {
      bf16x4 o;
      if (i < nv) {
        float4 v = vals[it];
        o[0] = (__bf16)(v.x * inv); o[1] = (__bf16)(v.y * inv);
        o[2] = (__bf16)(v.z * inv); o[3] = (__bf16)(v.w * inv);
      } else {
        o[0] = o[1] = o[2] = o[3] = (__bf16)0.0f;
      }
      *(bf16x4*)(prow + (i << 2)) = o;
    }
  }
}

// ---------------------------------------------------------------------------
// PV (batched z): out[v][s] = sum_{t<=s} P[s,t] * Vt[v,t], direct float4 store
// into the transposed output slice. P row stride 8192 bf16 (16KB).
// Depth-reflected across z: co-resident blocks {same (x,y), z=0..3} get depths
// {32-y, y+1, 32-y, y+1} (tile-units) -> constant 66 per pair: per-CU K-work
// is uniform regardless of block->CU assignment (LPT order alone did nothing:
// all 1024 blocks are co-resident, so only per-CU sums matter).
__global__ void pv_gemm_k(const __bf16* __restrict__ P, const __bf16* __restrict__ Vt,
                          float* __restrict__ outb) {
  P    += (size_t)blockIdx.z * P_STRIDE;
  Vt   += (size_t)blockIdx.z * XB_STRIDE;
  outb += (size_t)blockIdx.z * OUT_STRIDE;
  __shared__ __bf16 As[4096], Bs[4096];
  f32x4 acc[4][4] = {};
  int mi = (blockIdx.z & 1) ? blockIdx.y : 31 - blockIdx.y;   // depth reflection
  int m0 = mi * 128, n0 = blockIdx.x * 128;
  gemm128_core(P, 8192, m0, Vt, 4096, n0, 0, m0 + 128, As, Bs, acc);

  const int lane = threadIdx.x & 63;
  const int wid = threadIdx.x >> 6;
  const int wr = wid >> 1, wc = wid & 1;
  const int lr = lane & 15;
  const int lg = (lane >> 4) * 4;
#pragma unroll
  for (int m = 0; m < 4; m++) {
    int rs = m0 + wr * 64 + m * 16 + lg;
#pragma unroll
    for (int n = 0; n < 4; n++) {
      int col = n0 + wc * 64 + n * 16 + lr;   // v index
      *(f32x4*)(outb + (long)col * 4096 + rs) = acc[m][n];
    }
  }
}

// ---------------------------------------------------------------------------

static inline char* align256(char* p) {
  return (char*)(((uintptr_t)p + 255) & ~(uintptr_t)255);
}

extern "C" void kernel_launch(void* const* d_in, const int* in_sizes, int n_in,
                              void* d_out, int out_size, void* d_ws, size_t ws_size,
                              hipStream_t stream) {
  const float* input = (const float*)d_in[0];   // [4][1024][4096]
  const float* frame = (const float*)d_in[1];   // [4096]
  const float* Wq = (const float*)d_in[2];
  const float* bq = (const float*)d_in[3];
  const float* Wk = (const float*)d_in[4];
  const float* bk = (const float*)d_in[5];
  const float* Wv = (const float*)d_in[6];
  const float* bv = (const float*)d_in[7];
  const float* alibi = (const float*)d_in[8];
  float* out = (float*)d_out;                   // [4][2048][4096]

  // Batched (z=4) path needs: Wt 6MB + xb/Qb/Kb/Vt 4x8MB each + sc 4x67MB ~= 410MB
  const size_t NEED_BATCHED = (size_t)3072 * 1024 * 2 + 4096 +
                              4 * (4 * XB_STRIDE * 2) + 4 * SC_STRIDE * 4 + 2048;
  int NB = (ws_size >= NEED_BATCHED) ? 4 : 1;

  char* p = (char*)d_ws;
  __bf16* Wt = (__bf16*)p;  p += (size_t)3072 * 1024 * 2;
  float* bcat = (float*)p;  p += 3072 * 4;                    p = align256(p);
  __bf16* xb = (__bf16*)p;  p += NB * XB_STRIDE * 2;          p = align256(p);
  __bf16* Qb = (__bf16*)p;  p += NB * XB_STRIDE * 2;          p = align256(p);
  __bf16* Kb = (__bf16*)p;  p += NB * XB_STRIDE * 2;          p = align256(p);
  __bf16* Vt = (__bf16*)p;  p += NB * XB_STRIDE * 2;          p = align256(p);
  float* sc = (float*)p;    // NB x [4096][4096] fp32; P aliased into row halves

  transpose_w_k<<<dim3(32, 32, 3), dim3(32, 8), 0, stream>>>(Wq, Wk, Wv, Wt);
  bcat_k<<<12, 256, 0, stream>>>(bq, bk, bv, bcat);
  copy_in_k<<<16384, 256, 0, stream>>>((const float4*)input, (float4*)out);

  for (int b0 = 0; b0 < 4; b0 += NB) {
    const float* inb = input + (size_t)b0 * XB_STRIDE;
    float* outb = out + (size_t)b0 * OUT_STRIDE + (size_t)1024 * 4096;
    transpose_x_k<<<dim3(128, 32, NB), dim3(32, 8), 0, stream>>>(inb, xb);
    qkv_gemm_k<<<dim3(24, 32, NB), 256, 0, stream>>>(xb, Wt, bcat, Qb, Kb, Vt);
    qk_gemm_k<<<dim3(32, 32, NB), 256, 0, stream>>>(Qb, Kb, sc);
    softmax_k<<<dim3(4096, NB), 256, 0, stream>>>(sc, frame, alibi);
    pv_gemm_k<<<dim3(8, 32, NB), 256, 0, stream>>>((const __bf16*)((char*)sc + 8192), Vt, outb);
  }
}

// Round 6
// 502.339 us; speedup vs baseline: 1.9563x; 1.0024x over previous
//
#include <hip/hip_runtime.h>
#include <cstdint>

#define AS1 __attribute__((address_space(1)))
#define AS3 __attribute__((address_space(3)))

typedef __bf16 bf16x8 __attribute__((ext_vector_type(8)));
typedef __bf16 bf16x4 __attribute__((ext_vector_type(4)));
typedef float  f32x4  __attribute__((ext_vector_type(4)));

// Per-batch element strides
#define XB_STRIDE   4194304ul   // 4096*1024 bf16 (also Qb, Kb, Vt, input-slice fp32)
#define SC_STRIDE   16777216ul  // 4096*4096 fp32
#define P_STRIDE    33554432ul  // score batch stride in bf16 units
#define OUT_STRIDE  8388608ul   // 2048*4096 fp32

// ---------------------------------------------------------------------------
// Copy input [B][1024][4096] fp32 into top half of out [B][2048][4096]
__global__ void copy_in_k(const float4* __restrict__ in, float4* __restrict__ out) {
  int i = blockIdx.x * 256 + threadIdx.x;       // 4*1024*4096/4 = 4194304
  int b = i >> 20;
  int r = i & 1048575;
  out[(long)b * 2097152 + r] = in[i];
}

// input slice [1024][4096] fp32 -> xb [4096][1024] bf16 (tiled transpose), batched z
__global__ void transpose_x_k(const float* __restrict__ in, __bf16* __restrict__ out) {
  in  += (size_t)blockIdx.z * XB_STRIDE;
  out += (size_t)blockIdx.z * XB_STRIDE;
  __shared__ float t[32][33];
  int s0 = blockIdx.x * 32, c0 = blockIdx.y * 32;
  int tx = threadIdx.x, ty = threadIdx.y;
#pragma unroll
  for (int i = 0; i < 4; i++)
    t[ty + i * 8][tx] = in[(c0 + ty + i * 8) * 4096 + s0 + tx];
  __syncthreads();
#pragma unroll
  for (int i = 0; i < 4; i++)
    out[(s0 + ty + i * 8) * 1024 + c0 + tx] = (__bf16)t[tx][ty + i * 8];
}

// Wq/Wk/Wv [1024][1024] fp32 -> Wt [3072][1024] bf16 transposed, Q slice pre-scaled 1/32
__global__ void transpose_w_k(const float* __restrict__ Wq, const float* __restrict__ Wk,
                              const float* __restrict__ Wv, __bf16* __restrict__ Wt) {
  __shared__ float t[32][33];
  int sel = blockIdx.z;
  const float* W = sel == 0 ? Wq : (sel == 1 ? Wk : Wv);
  float scale = sel == 0 ? 0.03125f : 1.0f;
  int n0 = blockIdx.x * 32, c0 = blockIdx.y * 32;
  int tx = threadIdx.x, ty = threadIdx.y;
#pragma unroll
  for (int i = 0; i < 4; i++)
    t[ty + i * 8][tx] = W[(c0 + ty + i * 8) * 1024 + n0 + tx];
  __syncthreads();
#pragma unroll
  for (int i = 0; i < 4; i++)
    Wt[(sel * 1024 + n0 + ty + i * 8) * 1024 + c0 + tx] = (__bf16)(t[tx][ty + i * 8] * scale);
}

__global__ void bcat_k(const float* __restrict__ bq, const float* __restrict__ bk,
                       const float* __restrict__ bv, float* __restrict__ bcat) {
  int n = blockIdx.x * 256 + threadIdx.x;       // 3072 total
  float v = n < 1024 ? bq[n] * 0.03125f : (n < 2048 ? bk[n - 1024] : bv[n - 2048]);
  bcat[n] = v;
}

// ---------------------------------------------------------------------------
// 128x128 bf16 MFMA GEMM core, depth-2 pipelined (T3/T4: counted vmcnt, loads
// stay in flight across barriers; never vmcnt(0) in the main loop).
// 256 threads = 4 waves in 2x2, each wave 4x4 frags of 16x16x32, BK=32.
// A row-major [M][K] at m0; B^T row-major [N][K] at n0; nt = K/32 iters.
// LDS: As[2]/Bs[2] double buffers, 32 KB total -> 5 blocks/CU.
// Hazard discipline: vmcnt(4)+barrier before reading buf (RAW, all waves);
// lgkmcnt(0)+barrier before restaging buf (WAR, in-flight ds_reads);
// sched_barrier(0) pins around waits (compiler hoist hazard, guide rule #18).
// ---------------------------------------------------------------------------
__device__ __forceinline__ void gemm128_core(const __bf16* __restrict__ A, int lda, int m0,
                                             const __bf16* __restrict__ B, int ldb, int n0,
                                             int nt, __bf16 (*As)[4096], __bf16 (*Bs)[4096],
                                             f32x4 acc[4][4]) {
  const int tid = threadIdx.x;
  const int lane = tid & 63;
  const int wid = tid >> 6;
  const int wr = wid >> 1, wc = wid & 1;
  const int lr = lane & 15;
  const int lk = (lane >> 4) << 3;
  const int srow = tid >> 2;            // 0..63
  const int skq = (tid & 3) << 3;       // 0,8,16,24
  const __bf16* ga = A + (long)(m0 + srow) * lda + skq;
  const __bf16* gb = B + (long)(n0 + srow) * ldb + skq;

#define STAGE(t, j) do {                                                                                             \
    int k0_ = (t) * 32;                                                                                              \
    __builtin_amdgcn_global_load_lds((const AS1 void*)(ga + k0_),            (AS3 void*)(As[j] + tid * 8),        16, 0, 0); \
    __builtin_amdgcn_global_load_lds((const AS1 void*)(ga + k0_ + 64 * lda), (AS3 void*)(As[j] + tid * 8 + 2048), 16, 0, 0); \
    __builtin_amdgcn_global_load_lds((const AS1 void*)(gb + k0_),            (AS3 void*)(Bs[j] + tid * 8),        16, 0, 0); \
    __builtin_amdgcn_global_load_lds((const AS1 void*)(gb + k0_ + 64 * ldb), (AS3 void*)(Bs[j] + tid * 8 + 2048), 16, 0, 0); \
  } while (0)

  STAGE(0, 0);
  if (nt > 1) STAGE(1, 1);

  for (int t = 0; t < nt; ++t) {
    const int j = t & 1;
    // Wait for tile t's 4 loads only; tile t+1's stay in flight across the barrier.
    if (t + 1 < nt) asm volatile("s_waitcnt vmcnt(4)" ::: "memory");
    else            asm volatile("s_waitcnt vmcnt(0)" ::: "memory");
    __builtin_amdgcn_s_barrier();
    __builtin_amdgcn_sched_barrier(0);

    bf16x8 af[4], bfr[4];
#pragma unroll
    for (int m = 0; m < 4; m++)
      af[m] = *(const bf16x8*)(As[j] + (wr * 64 + m * 16 + lr) * 32 + lk);
#pragma unroll
    for (int n = 0; n < 4; n++)
      bfr[n] = *(const bf16x8*)(Bs[j] + (wc * 64 + n * 16 + lr) * 32 + lk);
#pragma unroll
    for (int m = 0; m < 4; m++)
#pragma unroll
      for (int n = 0; n < 4; n++)
        acc[m][n] = __builtin_amdgcn_mfma_f32_16x16x32_bf16(af[m], bfr[n], acc[m][n], 0, 0, 0);

    // All my ds_reads complete before signaling; then all waves done -> safe to restage.
    asm volatile("s_waitcnt lgkmcnt(0)" ::: "memory");
    __builtin_amdgcn_sched_barrier(0);
    __builtin_amdgcn_s_barrier();
    __builtin_amdgcn_sched_barrier(0);
    if (t + 2 < nt) STAGE(t + 2, j);
  }
#undef STAGE
}

// ---------------------------------------------------------------------------
// QKV fused projection (batched z): [4096 x 3072] = xb[4096x1024] @ Wt^T
__global__ void qkv_gemm_k(const __bf16* __restrict__ xb, const __bf16* __restrict__ Wt,
                           const float* __restrict__ bcat, __bf16* __restrict__ Qb,
                           __bf16* __restrict__ Kb, __bf16* __restrict__ Vt) {
  size_t zo = (size_t)blockIdx.z * XB_STRIDE;
  xb += zo; Qb += zo; Kb += zo; Vt += zo;
  __shared__ __bf16 As[2][4096], Bs[2][4096];
  f32x4 acc[4][4] = {};
  int m0 = blockIdx.y * 128, n0 = blockIdx.x * 128;
  gemm128_core(xb, 1024, m0, Wt, 1024, n0, 32, As, Bs, acc);

  const int lane = threadIdx.x & 63;
  const int wid = threadIdx.x >> 6;
  const int wr = wid >> 1, wc = wid & 1;
  const int lr = lane & 15;
  const int lg = (lane >> 4) * 4;
#pragma unroll
  for (int m = 0; m < 4; m++) {
    int rs = m0 + wr * 64 + m * 16 + lg;
#pragma unroll
    for (int n = 0; n < 4; n++) {
      int col = n0 + wc * 64 + n * 16 + lr;
      float bias = bcat[col];
      if (col < 1024) {
#pragma unroll
        for (int r = 0; r < 4; r++)
          Qb[(rs + r) * 1024 + col] = (__bf16)(acc[m][n][r] + bias);
      } else if (col < 2048) {
#pragma unroll
        for (int r = 0; r < 4; r++)
          Kb[(rs + r) * 1024 + (col - 1024)] = (__bf16)(acc[m][n][r] + bias);
      } else {
        bf16x4 t4;
#pragma unroll
        for (int r = 0; r < 4; r++) t4[r] = (__bf16)(acc[m][n][r] + bias);
        *(bf16x4*)(Vt + (long)(col - 2048) * 4096 + rs) = t4;
      }
    }
  }
}

// ---------------------------------------------------------------------------
// QK^T (batched z): scores[s][t] = Q[s,:]·K[t,:]. Upper-tri tiles skipped.
__global__ void qk_gemm_k(const __bf16* __restrict__ Qb, const __bf16* __restrict__ Kb,
                          float* __restrict__ sc) {
  if (blockIdx.x > blockIdx.y) return;
  size_t zo = (size_t)blockIdx.z * XB_STRIDE;
  Qb += zo; Kb += zo;
  sc += (size_t)blockIdx.z * SC_STRIDE;
  __shared__ __bf16 As[2][4096], Bs[2][4096];
  f32x4 acc[4][4] = {};
  int m0 = blockIdx.y * 128, n0 = blockIdx.x * 128;
  gemm128_core(Qb, 1024, m0, Kb, 1024, n0, 32, As, Bs, acc);

  const int lane = threadIdx.x & 63;
  const int wid = threadIdx.x >> 6;
  const int wr = wid >> 1, wc = wid & 1;
  const int lr = lane & 15;
  const int lg = (lane >> 4) * 4;
#pragma unroll
  for (int m = 0; m < 4; m++) {
    int rs = m0 + wr * 64 + m * 16 + lg;
#pragma unroll
    for (int n = 0; n < 4; n++) {
      int col = n0 + wc * 64 + n * 16 + lr;
#pragma unroll
      for (int r = 0; r < 4; r++)
        sc[(long)(rs + r) * 4096 + col] = acc[m][n][r];
    }
  }
}

// ---------------------------------------------------------------------------
// Row softmax, causal + alibi (batched: blockIdx.y). All row state lives in
// registers: each thread owns <=4 float4 chunks (statically indexed). P bf16
// is written in place into the second 8KB half of each 16KB score row, up to
// the causal tile bound round_up(s+1,128) that pv_gemm reads.
__global__ void softmax_k(float* __restrict__ sc, const float* __restrict__ frame,
                          const float* __restrict__ alibi_p) {
  sc += (size_t)blockIdx.y * SC_STRIDE;
  __shared__ float red[4];
  int s = blockIdx.x;
  float* srow = sc + (long)s * 4096;
  __bf16* prow = (__bf16*)(srow + 2048);
  int tid = threadIdx.x, lane = tid & 63, wid = tid >> 6;
  float sig = 1.0f / (1.0f + __expf(-alibi_p[0]));
  float fs = frame[s];
  int n = s + 1;
  int bound = ((s >> 7) + 1) << 7;     // multiple of 128; == kend read by pv
  int nv = (n + 3) >> 2;               // float4 chunks covering [0, n)
  int bv = bound >> 2;

  const float4* srow4 = (const float4*)srow;
  const float4* fr4 = (const float4*)frame;
  float4 vals[4];

  float mx = -3.4e38f;
#pragma unroll
  for (int it = 0; it < 4; it++) {
    int i = tid + it * 256;
    if (i < nv) {
      float4 v = srow4[i];
      float4 f = fr4[i];
      int t0 = i << 2;
      float a0 = (t0     < n) ? v.x - sig * fabsf(f.x - fs) : -3.4e38f;
      float a1 = (t0 + 1 < n) ? v.y - sig * fabsf(f.y - fs) : -3.4e38f;
      float a2 = (t0 + 2 < n) ? v.z - sig * fabsf(f.z - fs) : -3.4e38f;
      float a3 = (t0 + 3 < n) ? v.w - sig * fabsf(f.w - fs) : -3.4e38f;
      vals[it] = make_float4(a0, a1, a2, a3);
      mx = fmaxf(fmaxf(fmaxf(mx, a0), fmaxf(a1, a2)), a3);
    }
  }
#pragma unroll
  for (int o = 32; o; o >>= 1) mx = fmaxf(mx, __shfl_xor(mx, o, 64));
  if (lane == 0) red[wid] = mx;
  __syncthreads();
  mx = fmaxf(fmaxf(red[0], red[1]), fmaxf(red[2], red[3]));

  float sum = 0.0f;
#pragma unroll
  for (int it = 0; it < 4; it++) {
    int i = tid + it * 256;
    if (i < nv) {
      float4 v = vals[it];
      float e0 = __expf(v.x - mx), e1 = __expf(v.y - mx);
      float e2 = __expf(v.z - mx), e3 = __expf(v.w - mx);
      vals[it] = make_float4(e0, e1, e2, e3);
      sum += (e0 + e1) + (e2 + e3);
    }
  }
#pragma unroll
  for (int o = 32; o; o >>= 1) sum += __shfl_xor(sum, o, 64);
  __syncthreads();
  if (lane == 0) red[wid] = sum;
  __syncthreads();
  sum = red[0] + red[1] + red[2] + red[3];
  float inv = 1.0f / sum;

#pragma unroll
  for (int it = 0; it < 4; it++) {
    int i = tid + it * 256;
    if (i < bv) {
      bf16x4 o;
      if (i < nv) {
        float4 v = vals[it];
        o[0] = (__bf16)(v.x * inv); o[1] = (__bf16)(v.y * inv);
        o[2] = (__bf16)(v.z * inv); o[3] = (__bf16)(v.w * inv);
      } else {
        o[0] = o[1] = o[2] = o[3] = (__bf16)0.0f;
      }
      *(bf16x4*)(prow + (i << 2)) = o;
    }
  }
}

// ---------------------------------------------------------------------------
// PV (batched z): out[v][s] = sum_{t<=s} P[s,t] * Vt[v,t], direct float4 store
// into the transposed output slice. P row stride 8192 bf16 (16KB).
// Depth-reflected across z so per-CU K-work is uniform (round-5 win).
__global__ void pv_gemm_k(const __bf16* __restrict__ P, const __bf16* __restrict__ Vt,
                          float* __restrict__ outb) {
  P    += (size_t)blockIdx.z * P_STRIDE;
  Vt   += (size_t)blockIdx.z * XB_STRIDE;
  outb += (size_t)blockIdx.z * OUT_STRIDE;
  __shared__ __bf16 As[2][4096], Bs[2][4096];
  f32x4 acc[4][4] = {};
  int mi = (blockIdx.z & 1) ? blockIdx.y : 31 - blockIdx.y;   // depth reflection
  int m0 = mi * 128, n0 = blockIdx.x * 128;
  gemm128_core(P, 8192, m0, Vt, 4096, n0, (m0 + 128) / 32, As, Bs, acc);

  const int lane = threadIdx.x & 63;
  const int wid = threadIdx.x >> 6;
  const int wr = wid >> 1, wc = wid & 1;
  const int lr = lane & 15;
  const int lg = (lane >> 4) * 4;
#pragma unroll
  for (int m = 0; m < 4; m++) {
    int rs = m0 + wr * 64 + m * 16 + lg;
#pragma unroll
    for (int n = 0; n < 4; n++) {
      int col = n0 + wc * 64 + n * 16 + lr;   // v index
      *(f32x4*)(outb + (long)col * 4096 + rs) = acc[m][n];
    }
  }
}

// ---------------------------------------------------------------------------

static inline char* align256(char* p) {
  return (char*)(((uintptr_t)p + 255) & ~(uintptr_t)255);
}

extern "C" void kernel_launch(void* const* d_in, const int* in_sizes, int n_in,
                              void* d_out, int out_size, void* d_ws, size_t ws_size,
                              hipStream_t stream) {
  const float* input = (const float*)d_in[0];   // [4][1024][4096]
  const float* frame = (const float*)d_in[1];   // [4096]
  const float* Wq = (const float*)d_in[2];
  const float* bq = (const float*)d_in[3];
  const float* Wk = (const float*)d_in[4];
  const float* bk = (const float*)d_in[5];
  const float* Wv = (const float*)d_in[6];
  const float* bv = (const float*)d_in[7];
  const float* alibi = (const float*)d_in[8];
  float* out = (float*)d_out;                   // [4][2048][4096]

  // Batched (z=4) path needs: Wt 6MB + xb/Qb/Kb/Vt 4x8MB each + sc 4x67MB ~= 410MB
  const size_t NEED_BATCHED = (size_t)3072 * 1024 * 2 + 4096 +
                              4 * (4 * XB_STRIDE * 2) + 4 * SC_STRIDE * 4 + 2048;
  int NB = (ws_size >= NEED_BATCHED) ? 4 : 1;

  char* p = (char*)d_ws;
  __bf16* Wt = (__bf16*)p;  p += (size_t)3072 * 1024 * 2;
  float* bcat = (float*)p;  p += 3072 * 4;                    p = align256(p);
  __bf16* xb = (__bf16*)p;  p += NB * XB_STRIDE * 2;          p = align256(p);
  __bf16* Qb = (__bf16*)p;  p += NB * XB_STRIDE * 2;          p = align256(p);
  __bf16* Kb = (__bf16*)p;  p += NB * XB_STRIDE * 2;          p = align256(p);
  __bf16* Vt = (__bf16*)p;  p += NB * XB_STRIDE * 2;          p = align256(p);
  float* sc = (float*)p;    // NB x [4096][4096] fp32; P aliased into row halves

  transpose_w_k<<<dim3(32, 32, 3), dim3(32, 8), 0, stream>>>(Wq, Wk, Wv, Wt);
  bcat_k<<<12, 256, 0, stream>>>(bq, bk, bv, bcat);
  copy_in_k<<<16384, 256, 0, stream>>>((const float4*)input, (float4*)out);

  for (int b0 = 0; b0 < 4; b0 += NB) {
    const float* inb = input + (size_t)b0 * XB_STRIDE;
    float* outb = out + (size_t)b0 * OUT_STRIDE + (size_t)1024 * 4096;
    transpose_x_k<<<dim3(128, 32, NB), dim3(32, 8), 0, stream>>>(inb, xb);
    qkv_gemm_k<<<dim3(24, 32, NB), 256, 0, stream>>>(xb, Wt, bcat, Qb, Kb, Vt);
    qk_gemm_k<<<dim3(32, 32, NB), 256, 0, stream>>>(Qb, Kb, sc);
    softmax_k<<<dim3(4096, NB), 256, 0, stream>>>(sc, frame, alibi);
    pv_gemm_k<<<dim3(8, 32, NB), 256, 0, stream>>>((const __bf16*)((char*)sc + 8192), Vt, outb);
  }
}

// Round 7
// 469.051 us; speedup vs baseline: 2.0951x; 1.0710x over previous
//
#include <hip/hip_runtime.h>
#include <cstdint>

#define AS1 __attribute__((address_space(1)))
#define AS3 __attribute__((address_space(3)))

typedef __bf16 bf16x8 __attribute__((ext_vector_type(8)));
typedef __bf16 bf16x4 __attribute__((ext_vector_type(4)));
typedef float  f32x4  __attribute__((ext_vector_type(4)));

// Per-batch element strides
#define XB_STRIDE   4194304ul   // 4096*1024 bf16 (also Qb, Kb, Vt, input-slice fp32)
#define SC_STRIDE   16777216ul  // 4096*4096 fp32
#define P_STRIDE    33554432ul  // score batch stride in bf16 units
#define OUT_STRIDE  8388608ul   // 2048*4096 fp32

// ---------------------------------------------------------------------------
// Copy input [B][1024][4096] fp32 into top half of out [B][2048][4096]
__global__ void copy_in_k(const float4* __restrict__ in, float4* __restrict__ out) {
  int i = blockIdx.x * 256 + threadIdx.x;       // 4*1024*4096/4 = 4194304
  int b = i >> 20;
  int r = i & 1048575;
  out[(long)b * 2097152 + r] = in[i];
}

// input slice [1024][4096] fp32 -> xb [4096][1024] bf16 (tiled transpose), batched z
__global__ void transpose_x_k(const float* __restrict__ in, __bf16* __restrict__ out) {
  in  += (size_t)blockIdx.z * XB_STRIDE;
  out += (size_t)blockIdx.z * XB_STRIDE;
  __shared__ float t[32][33];
  int s0 = blockIdx.x * 32, c0 = blockIdx.y * 32;
  int tx = threadIdx.x, ty = threadIdx.y;
#pragma unroll
  for (int i = 0; i < 4; i++)
    t[ty + i * 8][tx] = in[(c0 + ty + i * 8) * 4096 + s0 + tx];
  __syncthreads();
#pragma unroll
  for (int i = 0; i < 4; i++)
    out[(s0 + ty + i * 8) * 1024 + c0 + tx] = (__bf16)t[tx][ty + i * 8];
}

// Wq/Wk/Wv [1024][1024] fp32 -> Wt [3072][1024] bf16 transposed, Q slice pre-scaled 1/32
__global__ void transpose_w_k(const float* __restrict__ Wq, const float* __restrict__ Wk,
                              const float* __restrict__ Wv, __bf16* __restrict__ Wt) {
  __shared__ float t[32][33];
  int sel = blockIdx.z;
  const float* W = sel == 0 ? Wq : (sel == 1 ? Wk : Wv);
  float scale = sel == 0 ? 0.03125f : 1.0f;
  int n0 = blockIdx.x * 32, c0 = blockIdx.y * 32;
  int tx = threadIdx.x, ty = threadIdx.y;
#pragma unroll
  for (int i = 0; i < 4; i++)
    t[ty + i * 8][tx] = W[(c0 + ty + i * 8) * 1024 + n0 + tx];
  __syncthreads();
#pragma unroll
  for (int i = 0; i < 4; i++)
    Wt[(sel * 1024 + n0 + ty + i * 8) * 1024 + c0 + tx] = (__bf16)(t[tx][ty + i * 8] * scale);
}

__global__ void bcat_k(const float* __restrict__ bq, const float* __restrict__ bk,
                       const float* __restrict__ bv, float* __restrict__ bcat) {
  int n = blockIdx.x * 256 + threadIdx.x;       // 3072 total
  float v = n < 1024 ? bq[n] * 0.03125f : (n < 2048 ? bk[n - 1024] : bv[n - 2048]);
  bcat[n] = v;
}

// ---------------------------------------------------------------------------
// 256x256 8-phase BK=64 GEMM core (m201-style template): 512 threads = 8 waves
// (2M x 4N), per-wave 128x64 output = acc[8][4] of 16x16x32 frags.
// LDS 128KB: buf[2] x { A:[2 halves][128][64], B:[2 halves][128][64] } bf16.
// Per K-tile, 4 phases; phase p computes quadrant (mh=p>>1, nh=p&1).
// Staging (1 half-tile per phase, counted vmcnt(4) once per tile, never 0 in
// steady state): ph0:A1[t+1]  ph1:B1[t+1]  ph2:B0[t+2]  ph3:A0[t+2].
// Restage-safety: B halves last ds_read ph1, A halves ph2; each restage is
// >=1 barrier after its region's last read. vmcnt(4) at ph3 leaves exactly
// {B0,A0}[t+2] (4 loads) in flight -> tile t+1 fully landed at its ph0.
// T2 swizzle (both-sides involution, rule #21): gload_lds writes linearly,
// global SOURCE col pre-swizzled (col16 ^= row&7); ds_read applies
// byte ^= ((row&7)<<4). Consecutive lane octets hit 8 distinct 16B groups.
// ---------------------------------------------------------------------------
template<int MH, int NH>
__device__ __forceinline__ void mf_quad(f32x4 (&acc)[8][4], bf16x8 (&aR)[4][2],
                                        bf16x8 (&br)[2][2]) {
#pragma unroll
  for (int q = 0; q < 4; q++)
#pragma unroll
    for (int r = 0; r < 2; r++) {
      acc[MH * 4 + q][NH * 2 + r] = __builtin_amdgcn_mfma_f32_16x16x32_bf16(
          aR[q][0], br[r][0], acc[MH * 4 + q][NH * 2 + r], 0, 0, 0);
      acc[MH * 4 + q][NH * 2 + r] = __builtin_amdgcn_mfma_f32_16x16x32_bf16(
          aR[q][1], br[r][1], acc[MH * 4 + q][NH * 2 + r], 0, 0, 0);
    }
}

__device__ __forceinline__ void gemm256_core(const __bf16* __restrict__ A, int lda, int m0,
                                             const __bf16* __restrict__ B, int ldb, int n0,
                                             __bf16* lds, f32x4 (&acc)[8][4]) {
  const int tid = threadIdx.x;
  const int l = tid & 63;
  const int w = tid >> 6;              // 0..7
  const int wm = w >> 2, wn = w & 3;   // wave 2x4
  const int lr = l & 15, kg = l >> 4;
  const int lrow = l >> 3;             // row within 8-row chunk
  const int scol = ((l & 7) ^ lrow) << 3;       // pre-swizzled source col (elems)
  const int xorv = (lr & 7) << 4;               // read-side swizzle
  const int cc0 = (kg << 4) ^ xorv;             // ks=0 col byte (swizzled)
  const int cc1 = (64 | (kg << 4)) ^ xorv;      // ks=1
  const int ch = w * 2;                          // chunk base (2 chunks/wave)
  const char* ldsA = (const char*)lds + wm * 16384;
  const char* ldsB = (const char*)lds + 32768 + (wn >> 1) * 16384;
  const int browb = (wn & 1) * 64;

#define STG8(PTR, LD, BASE0, H, TT, JB, OPOFF) do {                                              \
    const __bf16* sp_ = (PTR) + (size_t)((BASE0) + (H) * 128 + ch * 8 + lrow) * (LD) +           \
                        (TT) * 64 + scol;                                                        \
    __bf16* dp_ = lds + ((JB) * 32768 + (OPOFF) + (H) * 8192 + ch * 512);                        \
    __builtin_amdgcn_global_load_lds((const AS1 void*)sp_,                   (AS3 void*)dp_,         16, 0, 0); \
    __builtin_amdgcn_global_load_lds((const AS1 void*)(sp_ + (size_t)8 * (LD)), (AS3 void*)(dp_ + 512), 16, 0, 0); \
  } while (0)
#define STGA(H, TT, JB) STG8(A, lda, m0, H, TT, JB, 0)
#define STGB(H, TT, JB) STG8(B, ldb, n0, H, TT, JB, 16384)
#define LDAF(dst, MH_, Q_) do {                                                                  \
    const char* p_ = ldsA + jbyte + ((MH_) * 64 + (Q_) * 16 + lr) * 128;                         \
    (dst)[0] = *(const bf16x8*)(p_ + cc0);                                                       \
    (dst)[1] = *(const bf16x8*)(p_ + cc1);                                                       \
  } while (0)
#define LDBF(dst, NH_, R_) do {                                                                  \
    const char* p_ = ldsB + jbyte + (browb + ((NH_) * 2 + (R_)) * 16 + lr) * 128;                \
    (dst)[0] = *(const bf16x8*)(p_ + cc0);                                                       \
    (dst)[1] = *(const bf16x8*)(p_ + cc1);                                                       \
  } while (0)
#define PHSYNC do { __builtin_amdgcn_s_barrier();                                                \
    asm volatile("s_waitcnt lgkmcnt(0)" ::: "memory");                                           \
    __builtin_amdgcn_sched_barrier(0); } while (0)

  // Prologue: tile0 complete + {B0,A0}[1]; vmcnt(4) leaves the latter in flight.
  STGA(0, 0, 0); STGA(1, 0, 0); STGB(0, 0, 0); STGB(1, 0, 0);
  STGB(0, 1, 1); STGA(0, 1, 1);
  asm volatile("s_waitcnt vmcnt(4)" ::: "memory");
  __builtin_amdgcn_sched_barrier(0);
  __builtin_amdgcn_s_barrier();

  bf16x8 aR[4][2], b0r[2][2], b1r[2][2];
  for (int t = 0; t < 16; ++t) {
    const int j = t & 1, jo = j ^ 1;
    const int jbyte = j * 65536;
    // ---- phase 0: quadrant (mh0, nh0); 12 ds_reads; stage A1[t+1]
#pragma unroll
    for (int q = 0; q < 4; q++) LDAF(aR[q], 0, q);
#pragma unroll
    for (int r = 0; r < 2; r++) LDBF(b0r[r], 0, r);
    if (t < 15) STGA(1, t + 1, jo);
    PHSYNC;
    __builtin_amdgcn_s_setprio(1);
    mf_quad<0, 0>(acc, aR, b0r);
    __builtin_amdgcn_s_setprio(0);
    __builtin_amdgcn_s_barrier();
    // ---- phase 1: (mh0, nh1); 4 ds_reads; stage B1[t+1]
#pragma unroll
    for (int r = 0; r < 2; r++) LDBF(b1r[r], 1, r);
    if (t < 15) STGB(1, t + 1, jo);
    PHSYNC;
    __builtin_amdgcn_s_setprio(1);
    mf_quad<0, 1>(acc, aR, b1r);
    __builtin_amdgcn_s_setprio(0);
    __builtin_amdgcn_s_barrier();
    // ---- phase 2: (mh1, nh1); 8 ds_reads; stage B0[t+2]
#pragma unroll
    for (int q = 0; q < 4; q++) LDAF(aR[q], 1, q);
    if (t < 14) STGB(0, t + 2, j);
    PHSYNC;
    __builtin_amdgcn_s_setprio(1);
    mf_quad<1, 1>(acc, aR, b1r);
    __builtin_amdgcn_s_setprio(0);
    __builtin_amdgcn_s_barrier();
    // ---- phase 3: (mh1, nh0); 0 ds_reads; stage A0[t+2]; counted vmcnt
    if (t < 14) STGA(0, t + 2, j);
    __builtin_amdgcn_s_barrier();
    __builtin_amdgcn_s_setprio(1);
    mf_quad<1, 0>(acc, aR, b0r);
    __builtin_amdgcn_s_setprio(0);
    if (t < 14) asm volatile("s_waitcnt vmcnt(4)" ::: "memory");
    else        asm volatile("s_waitcnt vmcnt(0)" ::: "memory");
    __builtin_amdgcn_sched_barrier(0);
    __builtin_amdgcn_s_barrier();
  }
#undef STG8
#undef STGA
#undef STGB
#undef LDAF
#undef LDBF
#undef PHSYNC
}

// ---------------------------------------------------------------------------
// QKV fused projection (batched z), 256x256 8-phase: [4096 x 3072] = xb @ Wt^T
__global__ void __launch_bounds__(512, 1)
qkv_gemm_k(const __bf16* __restrict__ xb, const __bf16* __restrict__ Wt,
           const float* __restrict__ bcat, __bf16* __restrict__ Qb,
           __bf16* __restrict__ Kb, __bf16* __restrict__ Vt) {
  size_t zo = (size_t)blockIdx.z * XB_STRIDE;
  xb += zo; Qb += zo; Kb += zo; Vt += zo;
  __shared__ __bf16 lds[65536];   // 128 KB
  f32x4 acc[8][4] = {};
  int m0 = blockIdx.y * 256, n0 = blockIdx.x * 256;
  gemm256_core(xb, 1024, m0, Wt, 1024, n0, lds, acc);

  const int l = threadIdx.x & 63;
  const int w = threadIdx.x >> 6;
  const int wm = w >> 2, wn = w & 3;
  const int lr = l & 15;
  const int lg = (l >> 4) * 4;
#pragma unroll
  for (int am = 0; am < 8; am++) {
    int rs = m0 + wm * 128 + am * 16 + lg;
#pragma unroll
    for (int an = 0; an < 4; an++) {
      int col = n0 + wn * 64 + an * 16 + lr;
      float bias = bcat[col];
      if (col < 1024) {
#pragma unroll
        for (int r = 0; r < 4; r++)
          Qb[(rs + r) * 1024 + col] = (__bf16)(acc[am][an][r] + bias);
      } else if (col < 2048) {
#pragma unroll
        for (int r = 0; r < 4; r++)
          Kb[(rs + r) * 1024 + (col - 1024)] = (__bf16)(acc[am][an][r] + bias);
      } else {
        bf16x4 t4;
#pragma unroll
        for (int r = 0; r < 4; r++) t4[r] = (__bf16)(acc[am][an][r] + bias);
        *(bf16x4*)(Vt + (size_t)(col - 2048) * 4096 + rs) = t4;
      }
    }
  }
}

// ---------------------------------------------------------------------------
// QK^T (batched z), 256x256 8-phase. Upper-tri 256-tiles skipped.
__global__ void __launch_bounds__(512, 1)
qk_gemm_k(const __bf16* __restrict__ Qb, const __bf16* __restrict__ Kb,
          float* __restrict__ sc) {
  if (blockIdx.x > blockIdx.y) return;
  size_t zo = (size_t)blockIdx.z * XB_STRIDE;
  Qb += zo; Kb += zo;
  sc += (size_t)blockIdx.z * SC_STRIDE;
  __shared__ __bf16 lds[65536];   // 128 KB
  f32x4 acc[8][4] = {};
  int m0 = blockIdx.y * 256, n0 = blockIdx.x * 256;
  gemm256_core(Qb, 1024, m0, Kb, 1024, n0, lds, acc);

  const int l = threadIdx.x & 63;
  const int w = threadIdx.x >> 6;
  const int wm = w >> 2, wn = w & 3;
  const int lr = l & 15;
  const int lg = (l >> 4) * 4;
#pragma unroll
  for (int am = 0; am < 8; am++) {
    int rs = m0 + wm * 128 + am * 16 + lg;
#pragma unroll
    for (int an = 0; an < 4; an++) {
      int col = n0 + wn * 64 + an * 16 + lr;
#pragma unroll
      for (int r = 0; r < 4; r++)
        sc[(size_t)(rs + r) * 4096 + col] = acc[am][an][r];
    }
  }
}

// ---------------------------------------------------------------------------
// 128x128 depth-2 pipelined core (round-6), kept for PV.
__device__ __forceinline__ void gemm128_core(const __bf16* __restrict__ A, int lda, int m0,
                                             const __bf16* __restrict__ B, int ldb, int n0,
                                             int nt, __bf16 (*As)[4096], __bf16 (*Bs)[4096],
                                             f32x4 acc[4][4]) {
  const int tid = threadIdx.x;
  const int lane = tid & 63;
  const int wid = tid >> 6;
  const int wr = wid >> 1, wc = wid & 1;
  const int lr = lane & 15;
  const int lk = (lane >> 4) << 3;
  const int srow = tid >> 2;
  const int skq = (tid & 3) << 3;
  const __bf16* ga = A + (long)(m0 + srow) * lda + skq;
  const __bf16* gb = B + (long)(n0 + srow) * ldb + skq;

#define STAGE(t, j) do {                                                                                             \
    int k0_ = (t) * 32;                                                                                              \
    __builtin_amdgcn_global_load_lds((const AS1 void*)(ga + k0_),            (AS3 void*)(As[j] + tid * 8),        16, 0, 0); \
    __builtin_amdgcn_global_load_lds((const AS1 void*)(ga + k0_ + 64 * lda), (AS3 void*)(As[j] + tid * 8 + 2048), 16, 0, 0); \
    __builtin_amdgcn_global_load_lds((const AS1 void*)(gb + k0_),            (AS3 void*)(Bs[j] + tid * 8),        16, 0, 0); \
    __builtin_amdgcn_global_load_lds((const AS1 void*)(gb + k0_ + 64 * ldb), (AS3 void*)(Bs[j] + tid * 8 + 2048), 16, 0, 0); \
  } while (0)

  STAGE(0, 0);
  if (nt > 1) STAGE(1, 1);

  for (int t = 0; t < nt; ++t) {
    const int j = t & 1;
    if (t + 1 < nt) asm volatile("s_waitcnt vmcnt(4)" ::: "memory");
    else            asm volatile("s_waitcnt vmcnt(0)" ::: "memory");
    __builtin_amdgcn_s_barrier();
    __builtin_amdgcn_sched_barrier(0);

    bf16x8 af[4], bfr[4];
#pragma unroll
    for (int m = 0; m < 4; m++)
      af[m] = *(const bf16x8*)(As[j] + (wr * 64 + m * 16 + lr) * 32 + lk);
#pragma unroll
    for (int n = 0; n < 4; n++)
      bfr[n] = *(const bf16x8*)(Bs[j] + (wc * 64 + n * 16 + lr) * 32 + lk);
#pragma unroll
    for (int m = 0; m < 4; m++)
#pragma unroll
      for (int n = 0; n < 4; n++)
        acc[m][n] = __builtin_amdgcn_mfma_f32_16x16x32_bf16(af[m], bfr[n], acc[m][n], 0, 0, 0);

    asm volatile("s_waitcnt lgkmcnt(0)" ::: "memory");
    __builtin_amdgcn_sched_barrier(0);
    __builtin_amdgcn_s_barrier();
    __builtin_amdgcn_sched_barrier(0);
    if (t + 2 < nt) STAGE(t + 2, j);
  }
#undef STAGE
}

// ---------------------------------------------------------------------------
// Row softmax, causal + alibi (batched: blockIdx.y). Register-resident rows;
// P bf16 written in place into the second 8KB half of each 16KB score row.
__global__ void softmax_k(float* __restrict__ sc, const float* __restrict__ frame,
                          const float* __restrict__ alibi_p) {
  sc += (size_t)blockIdx.y * SC_STRIDE;
  __shared__ float red[4];
  int s = blockIdx.x;
  float* srow = sc + (long)s * 4096;
  __bf16* prow = (__bf16*)(srow + 2048);
  int tid = threadIdx.x, lane = tid & 63, wid = tid >> 6;
  float sig = 1.0f / (1.0f + __expf(-alibi_p[0]));
  float fs = frame[s];
  int n = s + 1;
  int bound = ((s >> 7) + 1) << 7;
  int nv = (n + 3) >> 2;
  int bv = bound >> 2;

  const float4* srow4 = (const float4*)srow;
  const float4* fr4 = (const float4*)frame;
  float4 vals[4];

  float mx = -3.4e38f;
#pragma unroll
  for (int it = 0; it < 4; it++) {
    int i = tid + it * 256;
    if (i < nv) {
      float4 v = srow4[i];
      float4 f = fr4[i];
      int t0 = i << 2;
      float a0 = (t0     < n) ? v.x - sig * fabsf(f.x - fs) : -3.4e38f;
      float a1 = (t0 + 1 < n) ? v.y - sig * fabsf(f.y - fs) : -3.4e38f;
      float a2 = (t0 + 2 < n) ? v.z - sig * fabsf(f.z - fs) : -3.4e38f;
      float a3 = (t0 + 3 < n) ? v.w - sig * fabsf(f.w - fs) : -3.4e38f;
      vals[it] = make_float4(a0, a1, a2, a3);
      mx = fmaxf(fmaxf(fmaxf(mx, a0), fmaxf(a1, a2)), a3);
    }
  }
#pragma unroll
  for (int o = 32; o; o >>= 1) mx = fmaxf(mx, __shfl_xor(mx, o, 64));
  if (lane == 0) red[wid] = mx;
  __syncthreads();
  mx = fmaxf(fmaxf(red[0], red[1]), fmaxf(red[2], red[3]));

  float sum = 0.0f;
#pragma unroll
  for (int it = 0; it < 4; it++) {
    int i = tid + it * 256;
    if (i < nv) {
      float4 v = vals[it];
      float e0 = __expf(v.x - mx), e1 = __expf(v.y - mx);
      float e2 = __expf(v.z - mx), e3 = __expf(v.w - mx);
      vals[it] = make_float4(e0, e1, e2, e3);
      sum += (e0 + e1) + (e2 + e3);
    }
  }
#pragma unroll
  for (int o = 32; o; o >>= 1) sum += __shfl_xor(sum, o, 64);
  __syncthreads();
  if (lane == 0) red[wid] = sum;
  __syncthreads();
  sum = red[0] + red[1] + red[2] + red[3];
  float inv = 1.0f / sum;

#pragma unroll
  for (int it = 0; it < 4; it++) {
    int i = tid + it * 256;
    if (i < bv) {
      bf16x4 o;
      if (i < nv) {
        float4 v = vals[it];
        o[0] = (__bf16)(v.x * inv); o[1] = (__bf16)(v.y * inv);
        o[2] = (__bf16)(v.z * inv); o[3] = (__bf16)(v.w * inv);
      } else {
        o[0] = o[1] = o[2] = o[3] = (__bf16)0.0f;
      }
      *(bf16x4*)(prow + (i << 2)) = o;
    }
  }
}

// ---------------------------------------------------------------------------
// PV (batched z): out[v][s] = sum_{t<=s} P[s,t] * Vt[v,t]; depth-reflected
// across z so per-CU K-work is uniform (round-5 win). 128^2 core.
__global__ void pv_gemm_k(const __bf16* __restrict__ P, const __bf16* __restrict__ Vt,
                          float* __restrict__ outb) {
  P    += (size_t)blockIdx.z * P_STRIDE;
  Vt   += (size_t)blockIdx.z * XB_STRIDE;
  outb += (size_t)blockIdx.z * OUT_STRIDE;
  __shared__ __bf16 As[2][4096], Bs[2][4096];
  f32x4 acc[4][4] = {};
  int mi = (blockIdx.z & 1) ? blockIdx.y : 31 - blockIdx.y;   // depth reflection
  int m0 = mi * 128, n0 = blockIdx.x * 128;
  gemm128_core(P, 8192, m0, Vt, 4096, n0, (m0 + 128) / 32, As, Bs, acc);

  const int lane = threadIdx.x & 63;
  const int wid = threadIdx.x >> 6;
  const int wr = wid >> 1, wc = wid & 1;
  const int lr = lane & 15;
  const int lg = (lane >> 4) * 4;
#pragma unroll
  for (int m = 0; m < 4; m++) {
    int rs = m0 + wr * 64 + m * 16 + lg;
#pragma unroll
    for (int n = 0; n < 4; n++) {
      int col = n0 + wc * 64 + n * 16 + lr;   // v index
      *(f32x4*)(outb + (long)col * 4096 + rs) = acc[m][n];
    }
  }
}

// ---------------------------------------------------------------------------

static inline char* align256(char* p) {
  return (char*)(((uintptr_t)p + 255) & ~(uintptr_t)255);
}

extern "C" void kernel_launch(void* const* d_in, const int* in_sizes, int n_in,
                              void* d_out, int out_size, void* d_ws, size_t ws_size,
                              hipStream_t stream) {
  const float* input = (const float*)d_in[0];   // [4][1024][4096]
  const float* frame = (const float*)d_in[1];   // [4096]
  const float* Wq = (const float*)d_in[2];
  const float* bq = (const float*)d_in[3];
  const float* Wk = (const float*)d_in[4];
  const float* bk = (const float*)d_in[5];
  const float* Wv = (const float*)d_in[6];
  const float* bv = (const float*)d_in[7];
  const float* alibi = (const float*)d_in[8];
  float* out = (float*)d_out;                   // [4][2048][4096]

  const size_t NEED_BATCHED = (size_t)3072 * 1024 * 2 + 4096 +
                              4 * (4 * XB_STRIDE * 2) + 4 * SC_STRIDE * 4 + 2048;
  int NB = (ws_size >= NEED_BATCHED) ? 4 : 1;

  char* p = (char*)d_ws;
  __bf16* Wt = (__bf16*)p;  p += (size_t)3072 * 1024 * 2;
  float* bcat = (float*)p;  p += 3072 * 4;                    p = align256(p);
  __bf16* xb = (__bf16*)p;  p += NB * XB_STRIDE * 2;          p = align256(p);
  __bf16* Qb = (__bf16*)p;  p += NB * XB_STRIDE * 2;          p = align256(p);
  __bf16* Kb = (__bf16*)p;  p += NB * XB_STRIDE * 2;          p = align256(p);
  __bf16* Vt = (__bf16*)p;  p += NB * XB_STRIDE * 2;          p = align256(p);
  float* sc = (float*)p;    // NB x [4096][4096] fp32; P aliased into row halves

  transpose_w_k<<<dim3(32, 32, 3), dim3(32, 8), 0, stream>>>(Wq, Wk, Wv, Wt);
  bcat_k<<<12, 256, 0, stream>>>(bq, bk, bv, bcat);
  copy_in_k<<<16384, 256, 0, stream>>>((const float4*)input, (float4*)out);

  for (int b0 = 0; b0 < 4; b0 += NB) {
    const float* inb = input + (size_t)b0 * XB_STRIDE;
    float* outb = out + (size_t)b0 * OUT_STRIDE + (size_t)1024 * 4096;
    transpose_x_k<<<dim3(128, 32, NB), dim3(32, 8), 0, stream>>>(inb, xb);
    qkv_gemm_k<<<dim3(12, 16, NB), 512, 0, stream>>>(xb, Wt, bcat, Qb, Kb, Vt);
    qk_gemm_k<<<dim3(16, 16, NB), 512, 0, stream>>>(Qb, Kb, sc);
    softmax_k<<<dim3(4096, NB), 256, 0, stream>>>(sc, frame, alibi);
    pv_gemm_k<<<dim3(8, 32, NB), 256, 0, stream>>>((const __bf16*)((char*)sc + 8192), Vt, outb);
  }
}

// Round 9
// 450.801 us; speedup vs baseline: 2.1800x; 1.0405x over previous
//
#include <hip/hip_runtime.h>
#include <cstdint>

#define AS1 __attribute__((address_space(1)))
#define AS3 __attribute__((address_space(3)))

typedef __bf16 bf16x8 __attribute__((ext_vector_type(8)));
typedef __bf16 bf16x4 __attribute__((ext_vector_type(4)));
typedef float  f32x4  __attribute__((ext_vector_type(4)));

// Per-batch element strides
#define XB_STRIDE   4194304ul   // 4096*1024 bf16 (also Qb, Kb, Vt, input-slice fp32)
#define SC_STRIDE   16777216ul  // 4096*4096 fp32
#define P_STRIDE    33554432ul  // score batch stride in bf16 units
#define OUT_STRIDE  8388608ul   // 2048*4096 fp32

// ---------------------------------------------------------------------------
// Copy input [B][1024][4096] fp32 into top half of out [B][2048][4096]
__global__ void copy_in_k(const float4* __restrict__ in, float4* __restrict__ out) {
  int i = blockIdx.x * 256 + threadIdx.x;       // 4*1024*4096/4 = 4194304
  int b = i >> 20;
  int r = i & 1048575;
  out[(long)b * 2097152 + r] = in[i];
}

// input slice [1024][4096] fp32 -> xb [4096][1024] bf16 (tiled transpose), batched z
__global__ void transpose_x_k(const float* __restrict__ in, __bf16* __restrict__ out) {
  in  += (size_t)blockIdx.z * XB_STRIDE;
  out += (size_t)blockIdx.z * XB_STRIDE;
  __shared__ float t[32][33];
  int s0 = blockIdx.x * 32, c0 = blockIdx.y * 32;
  int tx = threadIdx.x, ty = threadIdx.y;
#pragma unroll
  for (int i = 0; i < 4; i++)
    t[ty + i * 8][tx] = in[(c0 + ty + i * 8) * 4096 + s0 + tx];
  __syncthreads();
#pragma unroll
  for (int i = 0; i < 4; i++)
    out[(s0 + ty + i * 8) * 1024 + c0 + tx] = (__bf16)t[tx][ty + i * 8];
}

// Wq/Wk/Wv [1024][1024] fp32 -> Wt [3072][1024] bf16 transposed, Q slice pre-scaled 1/32
__global__ void transpose_w_k(const float* __restrict__ Wq, const float* __restrict__ Wk,
                              const float* __restrict__ Wv, __bf16* __restrict__ Wt) {
  __shared__ float t[32][33];
  int sel = blockIdx.z;
  const float* W = sel == 0 ? Wq : (sel == 1 ? Wk : Wv);
  float scale = sel == 0 ? 0.03125f : 1.0f;
  int n0 = blockIdx.x * 32, c0 = blockIdx.y * 32;
  int tx = threadIdx.x, ty = threadIdx.y;
#pragma unroll
  for (int i = 0; i < 4; i++)
    t[ty + i * 8][tx] = W[(c0 + ty + i * 8) * 1024 + n0 + tx];
  __syncthreads();
#pragma unroll
  for (int i = 0; i < 4; i++)
    Wt[(sel * 1024 + n0 + ty + i * 8) * 1024 + c0 + tx] = (__bf16)(t[tx][ty + i * 8] * scale);
}

__global__ void bcat_k(const float* __restrict__ bq, const float* __restrict__ bk,
                       const float* __restrict__ bv, float* __restrict__ bcat) {
  int n = blockIdx.x * 256 + threadIdx.x;       // 3072 total
  float v = n < 1024 ? bq[n] * 0.03125f : (n < 2048 ? bk[n - 1024] : bv[n - 2048]);
  bcat[n] = v;
}

// ---------------------------------------------------------------------------
// 256x256 8-phase BK=64 GEMM core (m201-style template): 512 threads = 8 waves
// (2M x 4N), per-wave 128x64 output = acc[8][4] of 16x16x32 frags.
// LDS 128KB: buf[2] x { A:[2 halves][128][64], B:[2 halves][128][64] } bf16.
// Verified round 7: SQ_LDS_BANK_CONFLICT == 0 with this swizzle.
// ---------------------------------------------------------------------------
template<int MH, int NH>
__device__ __forceinline__ void mf_quad(f32x4 (&acc)[8][4], bf16x8 (&aR)[4][2],
                                        bf16x8 (&br)[2][2]) {
#pragma unroll
  for (int q = 0; q < 4; q++)
#pragma unroll
    for (int r = 0; r < 2; r++) {
      acc[MH * 4 + q][NH * 2 + r] = __builtin_amdgcn_mfma_f32_16x16x32_bf16(
          aR[q][0], br[r][0], acc[MH * 4 + q][NH * 2 + r], 0, 0, 0);
      acc[MH * 4 + q][NH * 2 + r] = __builtin_amdgcn_mfma_f32_16x16x32_bf16(
          aR[q][1], br[r][1], acc[MH * 4 + q][NH * 2 + r], 0, 0, 0);
    }
}

__device__ __forceinline__ void gemm256_core(const __bf16* __restrict__ A, int lda, int m0,
                                             const __bf16* __restrict__ B, int ldb, int n0,
                                             __bf16* lds, f32x4 (&acc)[8][4]) {
  const int tid = threadIdx.x;
  const int l = tid & 63;
  const int w = tid >> 6;              // 0..7
  const int wm = w >> 2, wn = w & 3;   // wave 2x4
  const int lr = l & 15, kg = l >> 4;
  const int lrow = l >> 3;             // row within 8-row chunk
  const int scol = ((l & 7) ^ lrow) << 3;       // pre-swizzled source col (elems)
  const int xorv = (lr & 7) << 4;               // read-side swizzle
  const int cc0 = (kg << 4) ^ xorv;             // ks=0 col byte (swizzled)
  const int cc1 = (64 | (kg << 4)) ^ xorv;      // ks=1
  const int ch = w * 2;                          // chunk base (2 chunks/wave)
  const char* ldsA = (const char*)lds + wm * 16384;
  const char* ldsB = (const char*)lds + 32768 + (wn >> 1) * 16384;
  const int browb = (wn & 1) * 64;

#define STG8(PTR, LD, BASE0, H, TT, JB, OPOFF) do {                                              \
    const __bf16* sp_ = (PTR) + (size_t)((BASE0) + (H) * 128 + ch * 8 + lrow) * (LD) +           \
                        (TT) * 64 + scol;                                                        \
    __bf16* dp_ = lds + ((JB) * 32768 + (OPOFF) + (H) * 8192 + ch * 512);                        \
    __builtin_amdgcn_global_load_lds((const AS1 void*)sp_,                   (AS3 void*)dp_,         16, 0, 0); \
    __builtin_amdgcn_global_load_lds((const AS1 void*)(sp_ + (size_t)8 * (LD)), (AS3 void*)(dp_ + 512), 16, 0, 0); \
  } while (0)
#define STGA(H, TT, JB) STG8(A, lda, m0, H, TT, JB, 0)
#define STGB(H, TT, JB) STG8(B, ldb, n0, H, TT, JB, 16384)
#define LDAF(dst, MH_, Q_) do {                                                                  \
    const char* p_ = ldsA + jbyte + ((MH_) * 64 + (Q_) * 16 + lr) * 128;                         \
    (dst)[0] = *(const bf16x8*)(p_ + cc0);                                                       \
    (dst)[1] = *(const bf16x8*)(p_ + cc1);                                                       \
  } while (0)
#define LDBF(dst, NH_, R_) do {                                                                  \
    const char* p_ = ldsB + jbyte + (browb + ((NH_) * 2 + (R_)) * 16 + lr) * 128;                \
    (dst)[0] = *(const bf16x8*)(p_ + cc0);                                                       \
    (dst)[1] = *(const bf16x8*)(p_ + cc1);                                                       \
  } while (0)
#define PHSYNC do { __builtin_amdgcn_s_barrier();                                                \
    asm volatile("s_waitcnt lgkmcnt(0)" ::: "memory");                                           \
    __builtin_amdgcn_sched_barrier(0); } while (0)

  // Prologue: tile0 complete + {B0,A0}[1]; vmcnt(4) leaves the latter in flight.
  STGA(0, 0, 0); STGA(1, 0, 0); STGB(0, 0, 0); STGB(1, 0, 0);
  STGB(0, 1, 1); STGA(0, 1, 1);
  asm volatile("s_waitcnt vmcnt(4)" ::: "memory");
  __builtin_amdgcn_sched_barrier(0);
  __builtin_amdgcn_s_barrier();

  bf16x8 aR[4][2], b0r[2][2], b1r[2][2];
  for (int t = 0; t < 16; ++t) {
    const int j = t & 1, jo = j ^ 1;
    const int jbyte = j * 65536;
    // ---- phase 0: quadrant (mh0, nh0); 12 ds_reads; stage A1[t+1]
#pragma unroll
    for (int q = 0; q < 4; q++) LDAF(aR[q], 0, q);
#pragma unroll
    for (int r = 0; r < 2; r++) LDBF(b0r[r], 0, r);
    if (t < 15) STGA(1, t + 1, jo);
    PHSYNC;
    __builtin_amdgcn_s_setprio(1);
    mf_quad<0, 0>(acc, aR, b0r);
    __builtin_amdgcn_s_setprio(0);
    __builtin_amdgcn_s_barrier();
    // ---- phase 1: (mh0, nh1); 4 ds_reads; stage B1[t+1]
#pragma unroll
    for (int r = 0; r < 2; r++) LDBF(b1r[r], 1, r);
    if (t < 15) STGB(1, t + 1, jo);
    PHSYNC;
    __builtin_amdgcn_s_setprio(1);
    mf_quad<0, 1>(acc, aR, b1r);
    __builtin_amdgcn_s_setprio(0);
    __builtin_amdgcn_s_barrier();
    // ---- phase 2: (mh1, nh1); 8 ds_reads; stage B0[t+2]
#pragma unroll
    for (int q = 0; q < 4; q++) LDAF(aR[q], 1, q);
    if (t < 14) STGB(0, t + 2, j);
    PHSYNC;
    __builtin_amdgcn_s_setprio(1);
    mf_quad<1, 1>(acc, aR, b1r);
    __builtin_amdgcn_s_setprio(0);
    __builtin_amdgcn_s_barrier();
    // ---- phase 3: (mh1, nh0); 0 ds_reads; stage A0[t+2]; counted vmcnt
    if (t < 14) STGA(0, t + 2, j);
    __builtin_amdgcn_s_barrier();
    __builtin_amdgcn_s_setprio(1);
    mf_quad<1, 0>(acc, aR, b0r);
    __builtin_amdgcn_s_setprio(0);
    if (t < 14) asm volatile("s_waitcnt vmcnt(4)" ::: "memory");
    else        asm volatile("s_waitcnt vmcnt(0)" ::: "memory");
    __builtin_amdgcn_sched_barrier(0);
    __builtin_amdgcn_s_barrier();
  }
#undef STG8
#undef STGA
#undef STGB
#undef LDAF
#undef LDBF
#undef PHSYNC
}

// ---------------------------------------------------------------------------
// QKV fused projection (batched z), 256x256 8-phase: [4096 x 3072] = xb @ Wt^T
__global__ void __launch_bounds__(512, 1)
qkv_gemm_k(const __bf16* __restrict__ xb, const __bf16* __restrict__ Wt,
           const float* __restrict__ bcat, __bf16* __restrict__ Qb,
           __bf16* __restrict__ Kb, __bf16* __restrict__ Vt) {
  size_t zo = (size_t)blockIdx.z * XB_STRIDE;
  xb += zo; Qb += zo; Kb += zo; Vt += zo;
  __shared__ __bf16 lds[65536];   // 128 KB
  f32x4 acc[8][4] = {};
  int m0 = blockIdx.y * 256, n0 = blockIdx.x * 256;
  gemm256_core(xb, 1024, m0, Wt, 1024, n0, lds, acc);

  const int l = threadIdx.x & 63;
  const int w = threadIdx.x >> 6;
  const int wm = w >> 2, wn = w & 3;
  const int lr = l & 15;
  const int lg = (l >> 4) * 4;
#pragma unroll
  for (int am = 0; am < 8; am++) {
    int rs = m0 + wm * 128 + am * 16 + lg;
#pragma unroll
    for (int an = 0; an < 4; an++) {
      int col = n0 + wn * 64 + an * 16 + lr;
      float bias = bcat[col];
      if (col < 1024) {
#pragma unroll
        for (int r = 0; r < 4; r++)
          Qb[(rs + r) * 1024 + col] = (__bf16)(acc[am][an][r] + bias);
      } else if (col < 2048) {
#pragma unroll
        for (int r = 0; r < 4; r++)
          Kb[(rs + r) * 1024 + (col - 1024)] = (__bf16)(acc[am][an][r] + bias);
      } else {
        bf16x4 t4;
#pragma unroll
        for (int r = 0; r < 4; r++) t4[r] = (__bf16)(acc[am][an][r] + bias);
        *(bf16x4*)(Vt + (size_t)(col - 2048) * 4096 + rs) = t4;
      }
    }
  }
}

// ---------------------------------------------------------------------------
// QK^T (batched z), 256x256 8-phase. Upper-tri 256-tiles skipped.
__global__ void __launch_bounds__(512, 1)
qk_gemm_k(const __bf16* __restrict__ Qb, const __bf16* __restrict__ Kb,
          float* __restrict__ sc) {
  if (blockIdx.x > blockIdx.y) return;
  size_t zo = (size_t)blockIdx.z * XB_STRIDE;
  Qb += zo; Kb += zo;
  sc += (size_t)blockIdx.z * SC_STRIDE;
  __shared__ __bf16 lds[65536];   // 128 KB
  f32x4 acc[8][4] = {};
  int m0 = blockIdx.y * 256, n0 = blockIdx.x * 256;
  gemm256_core(Qb, 1024, m0, Kb, 1024, n0, lds, acc);

  const int l = threadIdx.x & 63;
  const int w = threadIdx.x >> 6;
  const int wm = w >> 2, wn = w & 3;
  const int lr = l & 15;
  const int lg = (l >> 4) * 4;
#pragma unroll
  for (int am = 0; am < 8; am++) {
    int rs = m0 + wm * 128 + am * 16 + lg;
#pragma unroll
    for (int an = 0; an < 4; an++) {
      int col = n0 + wn * 64 + an * 16 + lr;
#pragma unroll
      for (int r = 0; r < 4; r++)
        sc[(size_t)(rs + r) * 4096 + col] = acc[am][an][r];
    }
  }
}

// ---------------------------------------------------------------------------
// 128x128 depth-2 pipelined core (round-6), kept for PV.
__device__ __forceinline__ void gemm128_core(const __bf16* __restrict__ A, int lda, int m0,
                                             const __bf16* __restrict__ B, int ldb, int n0,
                                             int nt, __bf16 (*As)[4096], __bf16 (*Bs)[4096],
                                             f32x4 acc[4][4]) {
  const int tid = threadIdx.x;
  const int lane = tid & 63;
  const int wid = tid >> 6;
  const int wr = wid >> 1, wc = wid & 1;
  const int lr = lane & 15;
  const int lk = (lane >> 4) << 3;
  const int srow = tid >> 2;
  const int skq = (tid & 3) << 3;
  const __bf16* ga = A + (long)(m0 + srow) * lda + skq;
  const __bf16* gb = B + (long)(n0 + srow) * ldb + skq;

#define STAGE(t, j) do {                                                                                             \
    int k0_ = (t) * 32;                                                                                              \
    __builtin_amdgcn_global_load_lds((const AS1 void*)(ga + k0_),            (AS3 void*)(As[j] + tid * 8),        16, 0, 0); \
    __builtin_amdgcn_global_load_lds((const AS1 void*)(ga + k0_ + 64 * lda), (AS3 void*)(As[j] + tid * 8 + 2048), 16, 0, 0); \
    __builtin_amdgcn_global_load_lds((const AS1 void*)(gb + k0_),            (AS3 void*)(Bs[j] + tid * 8),        16, 0, 0); \
    __builtin_amdgcn_global_load_lds((const AS1 void*)(gb + k0_ + 64 * ldb), (AS3 void*)(Bs[j] + tid * 8 + 2048), 16, 0, 0); \
  } while (0)

  STAGE(0, 0);
  if (nt > 1) STAGE(1, 1);

  for (int t = 0; t < nt; ++t) {
    const int j = t & 1;
    if (t + 1 < nt) asm volatile("s_waitcnt vmcnt(4)" ::: "memory");
    else            asm volatile("s_waitcnt vmcnt(0)" ::: "memory");
    __builtin_amdgcn_s_barrier();
    __builtin_amdgcn_sched_barrier(0);

    bf16x8 af[4], bfr[4];
#pragma unroll
    for (int m = 0; m < 4; m++)
      af[m] = *(const bf16x8*)(As[j] + (wr * 64 + m * 16 + lr) * 32 + lk);
#pragma unroll
    for (int n = 0; n < 4; n++)
      bfr[n] = *(const bf16x8*)(Bs[j] + (wc * 64 + n * 16 + lr) * 32 + lk);
#pragma unroll
    for (int m = 0; m < 4; m++)
#pragma unroll
      for (int n = 0; n < 4; n++)
        acc[m][n] = __builtin_amdgcn_mfma_f32_16x16x32_bf16(af[m], bfr[n], acc[m][n], 0, 0, 0);

    asm volatile("s_waitcnt lgkmcnt(0)" ::: "memory");
    __builtin_amdgcn_sched_barrier(0);
    __builtin_amdgcn_s_barrier();
    __builtin_amdgcn_sched_barrier(0);
    if (t + 2 < nt) STAGE(t + 2, j);
  }
#undef STAGE
}

// ---------------------------------------------------------------------------
// Row softmax, causal + alibi (batched: blockIdx.y). Register-resident rows;
// P bf16 written in place into the second 8KB half of each 16KB score row.
__global__ void softmax_k(float* __restrict__ sc, const float* __restrict__ frame,
                          const float* __restrict__ alibi_p) {
  sc += (size_t)blockIdx.y * SC_STRIDE;
  __shared__ float red[4];
  int s = blockIdx.x;
  float* srow = sc + (long)s * 4096;
  __bf16* prow = (__bf16*)(srow + 2048);
  int tid = threadIdx.x, lane = tid & 63, wid = tid >> 6;
  float sig = 1.0f / (1.0f + __expf(-alibi_p[0]));
  float fs = frame[s];
  int n = s + 1;
  int bound = ((s >> 7) + 1) << 7;
  int nv = (n + 3) >> 2;
  int bv = bound >> 2;

  const float4* srow4 = (const float4*)srow;
  const float4* fr4 = (const float4*)frame;
  float4 vals[4];

  float mx = -3.4e38f;
#pragma unroll
  for (int it = 0; it < 4; it++) {
    int i = tid + it * 256;
    if (i < nv) {
      float4 v = srow4[i];
      float4 f = fr4[i];
      int t0 = i << 2;
      float a0 = (t0     < n) ? v.x - sig * fabsf(f.x - fs) : -3.4e38f;
      float a1 = (t0 + 1 < n) ? v.y - sig * fabsf(f.y - fs) : -3.4e38f;
      float a2 = (t0 + 2 < n) ? v.z - sig * fabsf(f.z - fs) : -3.4e38f;
      float a3 = (t0 + 3 < n) ? v.w - sig * fabsf(f.w - fs) : -3.4e38f;
      vals[it] = make_float4(a0, a1, a2, a3);
      mx = fmaxf(fmaxf(fmaxf(mx, a0), fmaxf(a1, a2)), a3);
    }
  }
#pragma unroll
  for (int o = 32; o; o >>= 1) mx = fmaxf(mx, __shfl_xor(mx, o, 64));
  if (lane == 0) red[wid] = mx;
  __syncthreads();
  mx = fmaxf(fmaxf(red[0], red[1]), fmaxf(red[2], red[3]));

  float sum = 0.0f;
#pragma unroll
  for (int it = 0; it < 4; it++) {
    int i = tid + it * 256;
    if (i < nv) {
      float4 v = vals[it];
      float e0 = __expf(v.x - mx), e1 = __expf(v.y - mx);
      float e2 = __expf(v.z - mx), e3 = __expf(v.w - mx);
      vals[it] = make_float4(e0, e1, e2, e3);
      sum += (e0 + e1) + (e2 + e3);
    }
  }
#pragma unroll
  for (int o = 32; o; o >>= 1) sum += __shfl_xor(sum, o, 64);
  __syncthreads();
  if (lane == 0) red[wid] = sum;
  __syncthreads();
  sum = red[0] + red[1] + red[2] + red[3];
  float inv = 1.0f / sum;

#pragma unroll
  for (int it = 0; it < 4; it++) {
    int i = tid + it * 256;
    if (i < bv) {
      bf16x4 o;
      if (i < nv) {
        float4 v = vals[it];
        o[0] = (__bf16)(v.x * inv); o[1] = (__bf16)(v.y * inv);
        o[2] = (__bf16)(v.z * inv); o[3] = (__bf16)(v.w * inv);
      } else {
        o[0] = o[1] = o[2] = o[3] = (__bf16)0.0f;
      }
      *(bf16x4*)(prow + (i << 2)) = o;
    }
  }
}

// ---------------------------------------------------------------------------
// PV (batched z): out[v][s] = sum_{t<=s} P[s,t] * Vt[v,t]; 128^2 core.
// Grid (32, 8, z): blockIdx.x = depth group, blockIdx.y = n-tile (v).
// XCD locality: linear id = bx + 32*by + 256*z -> id mod 8 = bx mod 8, so all
// 8 n-tile blocks sharing the P[mi] row-panel land on the SAME XCD (P fetched
// ~once per XCD, not 8x). Depth balance (round-5 property preserved): same-CU
// sets {id, id+256, id+512, id+768} = same (bx,by) across z -> depths
// {bx+1, 32-bx} pairs, constant sum. mi = (z&1) ? bx : 31-bx is bijective per z.
__global__ void pv_gemm_k(const __bf16* __restrict__ P, const __bf16* __restrict__ Vt,
                          float* __restrict__ outb) {
  int z = blockIdx.z;
  int mi = (z & 1) ? blockIdx.x : 31 - blockIdx.x;   // depth reflection
  int n0 = blockIdx.y * 128;
  P    += (size_t)z * P_STRIDE;
  Vt   += (size_t)z * XB_STRIDE;
  outb += (size_t)z * OUT_STRIDE;
  __shared__ __bf16 As[2][4096], Bs[2][4096];
  f32x4 acc[4][4] = {};
  int m0 = mi * 128;
  gemm128_core(P, 8192, m0, Vt, 4096, n0, (m0 + 128) / 32, As, Bs, acc);

  const int lane = threadIdx.x & 63;
  const int wid = threadIdx.x >> 6;
  const int wr = wid >> 1, wc = wid & 1;
  const int lr = lane & 15;
  const int lg = (lane >> 4) * 4;
#pragma unroll
  for (int m = 0; m < 4; m++) {
    int rs = m0 + wr * 64 + m * 16 + lg;
#pragma unroll
    for (int n = 0; n < 4; n++) {
      int col = n0 + wc * 64 + n * 16 + lr;   // v index
      *(f32x4*)(outb + (long)col * 4096 + rs) = acc[m][n];
    }
  }
}

// ---------------------------------------------------------------------------

static inline char* align256(char* p) {
  return (char*)(((uintptr_t)p + 255) & ~(uintptr_t)255);
}

extern "C" void kernel_launch(void* const* d_in, const int* in_sizes, int n_in,
                              void* d_out, int out_size, void* d_ws, size_t ws_size,
                              hipStream_t stream) {
  const float* input = (const float*)d_in[0];   // [4][1024][4096]
  const float* frame = (const float*)d_in[1];   // [4096]
  const float* Wq = (const float*)d_in[2];
  const float* bq = (const float*)d_in[3];
  const float* Wk = (const float*)d_in[4];
  const float* bk = (const float*)d_in[5];
  const float* Wv = (const float*)d_in[6];
  const float* bv = (const float*)d_in[7];
  const float* alibi = (const float*)d_in[8];
  float* out = (float*)d_out;                   // [4][2048][4096]

  const size_t NEED_BATCHED = (size_t)3072 * 1024 * 2 + 4096 +
                              4 * (4 * XB_STRIDE * 2) + 4 * SC_STRIDE * 4 + 2048;
  int NB = (ws_size >= NEED_BATCHED) ? 4 : 1;

  char* p = (char*)d_ws;
  __bf16* Wt = (__bf16*)p;  p += (size_t)3072 * 1024 * 2;
  float* bcat = (float*)p;  p += 3072 * 4;                    p = align256(p);
  __bf16* xb = (__bf16*)p;  p += NB * XB_STRIDE * 2;          p = align256(p);
  __bf16* Qb = (__bf16*)p;  p += NB * XB_STRIDE * 2;          p = align256(p);
  __bf16* Kb = (__bf16*)p;  p += NB * XB_STRIDE * 2;          p = align256(p);
  __bf16* Vt = (__bf16*)p;  p += NB * XB_STRIDE * 2;          p = align256(p);
  float* sc = (float*)p;    // NB x [4096][4096] fp32; P aliased into row halves

  transpose_w_k<<<dim3(32, 32, 3), dim3(32, 8), 0, stream>>>(Wq, Wk, Wv, Wt);
  bcat_k<<<12, 256, 0, stream>>>(bq, bk, bv, bcat);
  copy_in_k<<<16384, 256, 0, stream>>>((const float4*)input, (float4*)out);

  for (int b0 = 0; b0 < 4; b0 += NB) {
    const float* inb = input + (size_t)b0 * XB_STRIDE;
    float* outb = out + (size_t)b0 * OUT_STRIDE + (size_t)1024 * 4096;
    transpose_x_k<<<dim3(128, 32, NB), dim3(32, 8), 0, stream>>>(inb, xb);
    qkv_gemm_k<<<dim3(12, 16, NB), 512, 0, stream>>>(xb, Wt, bcat, Qb, Kb, Vt);
    qk_gemm_k<<<dim3(16, 16, NB), 512, 0, stream>>>(Qb, Kb, sc);
    softmax_k<<<dim3(4096, NB), 256, 0, stream>>>(sc, frame, alibi);
    pv_gemm_k<<<dim3(32, 8, NB), 256, 0, stream>>>((const __bf16*)((char*)sc + 8192), Vt, outb);
  }
}

// Round 10
// 444.542 us; speedup vs baseline: 2.2107x; 1.0141x over previous
//
#include <hip/hip_runtime.h>
#include <cstdint>

#define AS1 __attribute__((address_space(1)))
#define AS3 __attribute__((address_space(3)))

typedef __bf16 bf16x8 __attribute__((ext_vector_type(8)));
typedef __bf16 bf16x4 __attribute__((ext_vector_type(4)));
typedef float  f32x4  __attribute__((ext_vector_type(4)));

// Per-batch element strides
#define XB_STRIDE   4194304ul   // 4096*1024 bf16 (also Qb, Kb, Vt, input-slice fp32)
#define SC_STRIDE   16777216ul  // 4096*4096 fp32
#define P_STRIDE    33554432ul  // score batch stride in bf16 units
#define OUT_STRIDE  8388608ul   // 2048*4096 fp32

// ---------------------------------------------------------------------------
// Copy input [B][1024][4096] fp32 into top half of out [B][2048][4096]
__global__ void copy_in_k(const float4* __restrict__ in, float4* __restrict__ out) {
  int i = blockIdx.x * 256 + threadIdx.x;       // 4*1024*4096/4 = 4194304
  int b = i >> 20;
  int r = i & 1048575;
  out[(long)b * 2097152 + r] = in[i];
}

// input slice [1024][4096] fp32 -> xb [4096][1024] bf16 (tiled transpose), batched z
__global__ void transpose_x_k(const float* __restrict__ in, __bf16* __restrict__ out) {
  in  += (size_t)blockIdx.z * XB_STRIDE;
  out += (size_t)blockIdx.z * XB_STRIDE;
  __shared__ float t[32][33];
  int s0 = blockIdx.x * 32, c0 = blockIdx.y * 32;
  int tx = threadIdx.x, ty = threadIdx.y;
#pragma unroll
  for (int i = 0; i < 4; i++)
    t[ty + i * 8][tx] = in[(c0 + ty + i * 8) * 4096 + s0 + tx];
  __syncthreads();
#pragma unroll
  for (int i = 0; i < 4; i++)
    out[(s0 + ty + i * 8) * 1024 + c0 + tx] = (__bf16)t[tx][ty + i * 8];
}

// Wq/Wk/Wv [1024][1024] fp32 -> Wt [3072][1024] bf16 transposed, Q slice pre-scaled 1/32
__global__ void transpose_w_k(const float* __restrict__ Wq, const float* __restrict__ Wk,
                              const float* __restrict__ Wv, __bf16* __restrict__ Wt) {
  __shared__ float t[32][33];
  int sel = blockIdx.z;
  const float* W = sel == 0 ? Wq : (sel == 1 ? Wk : Wv);
  float scale = sel == 0 ? 0.03125f : 1.0f;
  int n0 = blockIdx.x * 32, c0 = blockIdx.y * 32;
  int tx = threadIdx.x, ty = threadIdx.y;
#pragma unroll
  for (int i = 0; i < 4; i++)
    t[ty + i * 8][tx] = W[(c0 + ty + i * 8) * 1024 + n0 + tx];
  __syncthreads();
#pragma unroll
  for (int i = 0; i < 4; i++)
    Wt[(sel * 1024 + n0 + ty + i * 8) * 1024 + c0 + tx] = (__bf16)(t[tx][ty + i * 8] * scale);
}

__global__ void bcat_k(const float* __restrict__ bq, const float* __restrict__ bk,
                       const float* __restrict__ bv, float* __restrict__ bcat) {
  int n = blockIdx.x * 256 + threadIdx.x;       // 3072 total
  float v = n < 1024 ? bq[n] * 0.03125f : (n < 2048 ? bk[n - 1024] : bv[n - 2048]);
  bcat[n] = v;
}

// ---------------------------------------------------------------------------
// 256x256 BK=64 GEMM core, STREAMING schedule (round 10): 512 threads = 8
// waves (2M x 4N), per-wave 128x64 output = acc[8][4] of 16x16x32 frags.
// LDS 128KB: buf[2] x { A:[2 halves][128][64], B:[2 halves][128][64] } bf16.
// Round-9 post-mortem: 4-phase lockstep (8 barriers + 4 full lgkmcnt(0) per
// K-tile) serialized the LDS pipe (~2260 cyc/K-tile) against the MFMA pipe
// (~2480 cyc/K-tile). This schedule issues ALL tile reads up front (legal:
// buffer fully resident at tile start), lets the COMPILER insert counted
// lgkmcnt before each MFMA quad (verified m97 behavior) so reads stream under
// MFMA issue, and keeps only the 2 barriers that ordering requires:
//  - mid-tile (after lgkmcnt(0)): all waves' reads of buf j done -> restage
//    {B0,A0}[t+2] into j is safe.
//  - tile end (after counted vmcnt): buf jo fully landed for tile t+1.
// Stage ledger per tile t (buf j): start: {A1,B1}[t+1]->jo (jo's A1/B1 were
// last read in t-1 before ITS mid lgkmcnt(0)+barrier); mid: {B0,A0}[t+2]->j.
// vmcnt at end: outstanding = start-4 + mid-4 = 8 -> wait 4 => {A1,B1}[t+1]
// and everything earlier landed. t=14 waits 0 (no mid-stage issued, must
// drain {A1,B1}[15]). Swizzle unchanged (round 7: bank conflicts == 0).
// ---------------------------------------------------------------------------
template<int MH, int NH>
__device__ __forceinline__ void mf_quad(f32x4 (&acc)[8][4], bf16x8 (&aR)[4][2],
                                        bf16x8 (&br)[2][2]) {
#pragma unroll
  for (int q = 0; q < 4; q++)
#pragma unroll
    for (int r = 0; r < 2; r++) {
      acc[MH * 4 + q][NH * 2 + r] = __builtin_amdgcn_mfma_f32_16x16x32_bf16(
          aR[q][0], br[r][0], acc[MH * 4 + q][NH * 2 + r], 0, 0, 0);
      acc[MH * 4 + q][NH * 2 + r] = __builtin_amdgcn_mfma_f32_16x16x32_bf16(
          aR[q][1], br[r][1], acc[MH * 4 + q][NH * 2 + r], 0, 0, 0);
    }
}

__device__ __forceinline__ void gemm256_core(const __bf16* __restrict__ A, int lda, int m0,
                                             const __bf16* __restrict__ B, int ldb, int n0,
                                             __bf16* lds, f32x4 (&acc)[8][4]) {
  const int tid = threadIdx.x;
  const int l = tid & 63;
  const int w = tid >> 6;              // 0..7
  const int wm = w >> 2, wn = w & 3;   // wave 2x4
  const int lr = l & 15, kg = l >> 4;
  const int lrow = l >> 3;             // row within 8-row chunk
  const int scol = ((l & 7) ^ lrow) << 3;       // pre-swizzled source col (elems)
  const int xorv = (lr & 7) << 4;               // read-side swizzle
  const int cc0 = (kg << 4) ^ xorv;             // ks=0 col byte (swizzled)
  const int cc1 = (64 | (kg << 4)) ^ xorv;      // ks=1
  const int ch = w * 2;                          // chunk base (2 chunks/wave)
  const char* ldsA = (const char*)lds + wm * 16384;
  const char* ldsB = (const char*)lds + 32768 + (wn >> 1) * 16384;
  const int browb = (wn & 1) * 64;

#define STG8(PTR, LD, BASE0, H, TT, JB, OPOFF) do {                                              \
    const __bf16* sp_ = (PTR) + (size_t)((BASE0) + (H) * 128 + ch * 8 + lrow) * (LD) +           \
                        (TT) * 64 + scol;                                                        \
    __bf16* dp_ = lds + ((JB) * 32768 + (OPOFF) + (H) * 8192 + ch * 512);                        \
    __builtin_amdgcn_global_load_lds((const AS1 void*)sp_,                   (AS3 void*)dp_,         16, 0, 0); \
    __builtin_amdgcn_global_load_lds((const AS1 void*)(sp_ + (size_t)8 * (LD)), (AS3 void*)(dp_ + 512), 16, 0, 0); \
  } while (0)
#define STGA(H, TT, JB) STG8(A, lda, m0, H, TT, JB, 0)
#define STGB(H, TT, JB) STG8(B, ldb, n0, H, TT, JB, 16384)
#define LDAF(dst, MH_, Q_) do {                                                                  \
    const char* p_ = ldsA + jbyte + ((MH_) * 64 + (Q_) * 16 + lr) * 128;                         \
    (dst)[0] = *(const bf16x8*)(p_ + cc0);                                                       \
    (dst)[1] = *(const bf16x8*)(p_ + cc1);                                                       \
  } while (0)
#define LDBF(dst, NH_, R_) do {                                                                  \
    const char* p_ = ldsB + jbyte + (browb + ((NH_) * 2 + (R_)) * 16 + lr) * 128;                \
    (dst)[0] = *(const bf16x8*)(p_ + cc0);                                                       \
    (dst)[1] = *(const bf16x8*)(p_ + cc1);                                                       \
  } while (0)

  // Prologue: tile0 complete + {B0,A0}[1]; vmcnt(4) leaves the latter in flight.
  STGA(0, 0, 0); STGA(1, 0, 0); STGB(0, 0, 0); STGB(1, 0, 0);
  STGB(0, 1, 1); STGA(0, 1, 1);
  asm volatile("s_waitcnt vmcnt(4)" ::: "memory");
  __builtin_amdgcn_sched_barrier(0);
  __builtin_amdgcn_s_barrier();

  bf16x8 aR[4][2], b0r[2][2], b1r[2][2];
  for (int t = 0; t < 16; ++t) {
    const int j = t & 1, jo = j ^ 1;
    const int jbyte = j * 65536;

    // ---- tile-t reads, first wave: A-half0 (8 b128) + both B halves (8 b128)
#pragma unroll
    for (int q = 0; q < 4; q++) LDAF(aR[q], 0, q);
#pragma unroll
    for (int r = 0; r < 2; r++) LDBF(b0r[r], 0, r);
#pragma unroll
    for (int r = 0; r < 2; r++) LDBF(b1r[r], 1, r);
    // stage next tile's A1,B1 into the other buffer (free since t-1 end barrier)
    if (t < 15) { STGA(1, t + 1, jo); STGB(1, t + 1, jo); }

    __builtin_amdgcn_s_setprio(1);
    mf_quad<0, 0>(acc, aR, b0r);     // compiler inserts counted lgkm waits
    mf_quad<0, 1>(acc, aR, b1r);
    __builtin_amdgcn_s_setprio(0);

    // ---- A-half1 reads (reuse aR registers)
#pragma unroll
    for (int q = 0; q < 4; q++) LDAF(aR[q], 1, q);
    __builtin_amdgcn_s_setprio(1);
    mf_quad<1, 1>(acc, aR, b1r);
    __builtin_amdgcn_s_setprio(0);

    // ---- mid-tile sync: all my reads done (explicit), then all waves' ->
    //      safe to restage B0/A0 regions of buf j for tile t+2.
    asm volatile("s_waitcnt lgkmcnt(0)" ::: "memory");
    __builtin_amdgcn_sched_barrier(0);
    __builtin_amdgcn_s_barrier();
    if (t < 14) { STGB(0, t + 2, j); STGA(0, t + 2, j); }

    __builtin_amdgcn_s_setprio(1);
    mf_quad<1, 0>(acc, aR, b0r);     // operands already register-resident
    __builtin_amdgcn_s_setprio(0);

    // ---- tile boundary: counted vmcnt (never 0 in steady state), barrier.
    if (t < 14) asm volatile("s_waitcnt vmcnt(4)" ::: "memory");
    else        asm volatile("s_waitcnt vmcnt(0)" ::: "memory");
    __builtin_amdgcn_sched_barrier(0);
    __builtin_amdgcn_s_barrier();
  }
#undef STG8
#undef STGA
#undef STGB
#undef LDAF
#undef LDBF
}

// ---------------------------------------------------------------------------
// QKV fused projection (batched z), 256x256 streaming: [4096 x 3072] = xb @ Wt^T
__global__ void __launch_bounds__(512, 1)
qkv_gemm_k(const __bf16* __restrict__ xb, const __bf16* __restrict__ Wt,
           const float* __restrict__ bcat, __bf16* __restrict__ Qb,
           __bf16* __restrict__ Kb, __bf16* __restrict__ Vt) {
  size_t zo = (size_t)blockIdx.z * XB_STRIDE;
  xb += zo; Qb += zo; Kb += zo; Vt += zo;
  __shared__ __bf16 lds[65536];   // 128 KB
  f32x4 acc[8][4] = {};
  int m0 = blockIdx.y * 256, n0 = blockIdx.x * 256;
  gemm256_core(xb, 1024, m0, Wt, 1024, n0, lds, acc);

  const int l = threadIdx.x & 63;
  const int w = threadIdx.x >> 6;
  const int wm = w >> 2, wn = w & 3;
  const int lr = l & 15;
  const int lg = (l >> 4) * 4;
#pragma unroll
  for (int am = 0; am < 8; am++) {
    int rs = m0 + wm * 128 + am * 16 + lg;
#pragma unroll
    for (int an = 0; an < 4; an++) {
      int col = n0 + wn * 64 + an * 16 + lr;
      float bias = bcat[col];
      if (col < 1024) {
#pragma unroll
        for (int r = 0; r < 4; r++)
          Qb[(rs + r) * 1024 + col] = (__bf16)(acc[am][an][r] + bias);
      } else if (col < 2048) {
#pragma unroll
        for (int r = 0; r < 4; r++)
          Kb[(rs + r) * 1024 + (col - 1024)] = (__bf16)(acc[am][an][r] + bias);
      } else {
        bf16x4 t4;
#pragma unroll
        for (int r = 0; r < 4; r++) t4[r] = (__bf16)(acc[am][an][r] + bias);
        *(bf16x4*)(Vt + (size_t)(col - 2048) * 4096 + rs) = t4;
      }
    }
  }
}

// ---------------------------------------------------------------------------
// QK^T (batched z), 256x256 streaming. Upper-tri 256-tiles skipped.
__global__ void __launch_bounds__(512, 1)
qk_gemm_k(const __bf16* __restrict__ Qb, const __bf16* __restrict__ Kb,
          float* __restrict__ sc) {
  if (blockIdx.x > blockIdx.y) return;
  size_t zo = (size_t)blockIdx.z * XB_STRIDE;
  Qb += zo; Kb += zo;
  sc += (size_t)blockIdx.z * SC_STRIDE;
  __shared__ __bf16 lds[65536];   // 128 KB
  f32x4 acc[8][4] = {};
  int m0 = blockIdx.y * 256, n0 = blockIdx.x * 256;
  gemm256_core(Qb, 1024, m0, Kb, 1024, n0, lds, acc);

  const int l = threadIdx.x & 63;
  const int w = threadIdx.x >> 6;
  const int wm = w >> 2, wn = w & 3;
  const int lr = l & 15;
  const int lg = (l >> 4) * 4;
#pragma unroll
  for (int am = 0; am < 8; am++) {
    int rs = m0 + wm * 128 + am * 16 + lg;
#pragma unroll
    for (int an = 0; an < 4; an++) {
      int col = n0 + wn * 64 + an * 16 + lr;
#pragma unroll
      for (int r = 0; r < 4; r++)
        sc[(size_t)(rs + r) * 4096 + col] = acc[am][an][r];
    }
  }
}

// ---------------------------------------------------------------------------
// 128x128 depth-2 pipelined core (round-6), kept for PV.
__device__ __forceinline__ void gemm128_core(const __bf16* __restrict__ A, int lda, int m0,
                                             const __bf16* __restrict__ B, int ldb, int n0,
                                             int nt, __bf16 (*As)[4096], __bf16 (*Bs)[4096],
                                             f32x4 acc[4][4]) {
  const int tid = threadIdx.x;
  const int lane = tid & 63;
  const int wid = tid >> 6;
  const int wr = wid >> 1, wc = wid & 1;
  const int lr = lane & 15;
  const int lk = (lane >> 4) << 3;
  const int srow = tid >> 2;
  const int skq = (tid & 3) << 3;
  const __bf16* ga = A + (long)(m0 + srow) * lda + skq;
  const __bf16* gb = B + (long)(n0 + srow) * ldb + skq;

#define STAGE(t, j) do {                                                                                             \
    int k0_ = (t) * 32;                                                                                              \
    __builtin_amdgcn_global_load_lds((const AS1 void*)(ga + k0_),            (AS3 void*)(As[j] + tid * 8),        16, 0, 0); \
    __builtin_amdgcn_global_load_lds((const AS1 void*)(ga + k0_ + 64 * lda), (AS3 void*)(As[j] + tid * 8 + 2048), 16, 0, 0); \
    __builtin_amdgcn_global_load_lds((const AS1 void*)(gb + k0_),            (AS3 void*)(Bs[j] + tid * 8),        16, 0, 0); \
    __builtin_amdgcn_global_load_lds((const AS1 void*)(gb + k0_ + 64 * ldb), (AS3 void*)(Bs[j] + tid * 8 + 2048), 16, 0, 0); \
  } while (0)

  STAGE(0, 0);
  if (nt > 1) STAGE(1, 1);

  for (int t = 0; t < nt; ++t) {
    const int j = t & 1;
    if (t + 1 < nt) asm volatile("s_waitcnt vmcnt(4)" ::: "memory");
    else            asm volatile("s_waitcnt vmcnt(0)" ::: "memory");
    __builtin_amdgcn_s_barrier();
    __builtin_amdgcn_sched_barrier(0);

    bf16x8 af[4], bfr[4];
#pragma unroll
    for (int m = 0; m < 4; m++)
      af[m] = *(const bf16x8*)(As[j] + (wr * 64 + m * 16 + lr) * 32 + lk);
#pragma unroll
    for (int n = 0; n < 4; n++)
      bfr[n] = *(const bf16x8*)(Bs[j] + (wc * 64 + n * 16 + lr) * 32 + lk);
#pragma unroll
    for (int m = 0; m < 4; m++)
#pragma unroll
      for (int n = 0; n < 4; n++)
        acc[m][n] = __builtin_amdgcn_mfma_f32_16x16x32_bf16(af[m], bfr[n], acc[m][n], 0, 0, 0);

    asm volatile("s_waitcnt lgkmcnt(0)" ::: "memory");
    __builtin_amdgcn_sched_barrier(0);
    __builtin_amdgcn_s_barrier();
    __builtin_amdgcn_sched_barrier(0);
    if (t + 2 < nt) STAGE(t + 2, j);
  }
#undef STAGE
}

// ---------------------------------------------------------------------------
// Row softmax, causal + alibi (batched: blockIdx.y). Register-resident rows;
// P bf16 written in place into the second 8KB half of each 16KB score row.
__global__ void softmax_k(float* __restrict__ sc, const float* __restrict__ frame,
                          const float* __restrict__ alibi_p) {
  sc += (size_t)blockIdx.y * SC_STRIDE;
  __shared__ float red[4];
  int s = blockIdx.x;
  float* srow = sc + (long)s * 4096;
  __bf16* prow = (__bf16*)(srow + 2048);
  int tid = threadIdx.x, lane = tid & 63, wid = tid >> 6;
  float sig = 1.0f / (1.0f + __expf(-alibi_p[0]));
  float fs = frame[s];
  int n = s + 1;
  int bound = ((s >> 7) + 1) << 7;
  int nv = (n + 3) >> 2;
  int bv = bound >> 2;

  const float4* srow4 = (const float4*)srow;
  const float4* fr4 = (const float4*)frame;
  float4 vals[4];

  float mx = -3.4e38f;
#pragma unroll
  for (int it = 0; it < 4; it++) {
    int i = tid + it * 256;
    if (i < nv) {
      float4 v = srow4[i];
      float4 f = fr4[i];
      int t0 = i << 2;
      float a0 = (t0     < n) ? v.x - sig * fabsf(f.x - fs) : -3.4e38f;
      float a1 = (t0 + 1 < n) ? v.y - sig * fabsf(f.y - fs) : -3.4e38f;
      float a2 = (t0 + 2 < n) ? v.z - sig * fabsf(f.z - fs) : -3.4e38f;
      float a3 = (t0 + 3 < n) ? v.w - sig * fabsf(f.w - fs) : -3.4e38f;
      vals[it] = make_float4(a0, a1, a2, a3);
      mx = fmaxf(fmaxf(fmaxf(mx, a0), fmaxf(a1, a2)), a3);
    }
  }
#pragma unroll
  for (int o = 32; o; o >>= 1) mx = fmaxf(mx, __shfl_xor(mx, o, 64));
  if (lane == 0) red[wid] = mx;
  __syncthreads();
  mx = fmaxf(fmaxf(red[0], red[1]), fmaxf(red[2], red[3]));

  float sum = 0.0f;
#pragma unroll
  for (int it = 0; it < 4; it++) {
    int i = tid + it * 256;
    if (i < nv) {
      float4 v = vals[it];
      float e0 = __expf(v.x - mx), e1 = __expf(v.y - mx);
      float e2 = __expf(v.z - mx), e3 = __expf(v.w - mx);
      vals[it] = make_float4(e0, e1, e2, e3);
      sum += (e0 + e1) + (e2 + e3);
    }
  }
#pragma unroll
  for (int o = 32; o; o >>= 1) sum += __shfl_xor(sum, o, 64);
  __syncthreads();
  if (lane == 0) red[wid] = sum;
  __syncthreads();
  sum = red[0] + red[1] + red[2] + red[3];
  float inv = 1.0f / sum;

#pragma unroll
  for (int it = 0; it < 4; it++) {
    int i = tid + it * 256;
    if (i < bv) {
      bf16x4 o;
      if (i < nv) {
        float4 v = vals[it];
        o[0] = (__bf16)(v.x * inv); o[1] = (__bf16)(v.y * inv);
        o[2] = (__bf16)(v.z * inv); o[3] = (__bf16)(v.w * inv);
      } else {
        o[0] = o[1] = o[2] = o[3] = (__bf16)0.0f;
      }
      *(bf16x4*)(prow + (i << 2)) = o;
    }
  }
}

// ---------------------------------------------------------------------------
// PV (batched z): out[v][s] = sum_{t<=s} P[s,t] * Vt[v,t]; 128^2 core.
// Grid (32, 8, z): blockIdx.x = depth group, blockIdx.y = n-tile (v).
// XCD locality (round-9 win): id mod 8 = bx mod 8 -> the 8 n-tile blocks
// sharing a P[mi] panel land on the same XCD. Depth reflection keeps per-CU
// K-work constant. mi = (z&1) ? bx : 31-bx is bijective per z.
__global__ void pv_gemm_k(const __bf16* __restrict__ P, const __bf16* __restrict__ Vt,
                          float* __restrict__ outb) {
  int z = blockIdx.z;
  int mi = (z & 1) ? blockIdx.x : 31 - blockIdx.x;   // depth reflection
  int n0 = blockIdx.y * 128;
  P    += (size_t)z * P_STRIDE;
  Vt   += (size_t)z * XB_STRIDE;
  outb += (size_t)z * OUT_STRIDE;
  __shared__ __bf16 As[2][4096], Bs[2][4096];
  f32x4 acc[4][4] = {};
  int m0 = mi * 128;
  gemm128_core(P, 8192, m0, Vt, 4096, n0, (m0 + 128) / 32, As, Bs, acc);

  const int lane = threadIdx.x & 63;
  const int wid = threadIdx.x >> 6;
  const int wr = wid >> 1, wc = wid & 1;
  const int lr = lane & 15;
  const int lg = (lane >> 4) * 4;
#pragma unroll
  for (int m = 0; m < 4; m++) {
    int rs = m0 + wr * 64 + m * 16 + lg;
#pragma unroll
    for (int n = 0; n < 4; n++) {
      int col = n0 + wc * 64 + n * 16 + lr;   // v index
      *(f32x4*)(outb + (long)col * 4096 + rs) = acc[m][n];
    }
  }
}

// ---------------------------------------------------------------------------

static inline char* align256(char* p) {
  return (char*)(((uintptr_t)p + 255) & ~(uintptr_t)255);
}

extern "C" void kernel_launch(void* const* d_in, const int* in_sizes, int n_in,
                              void* d_out, int out_size, void* d_ws, size_t ws_size,
                              hipStream_t stream) {
  const float* input = (const float*)d_in[0];   // [4][1024][4096]
  const float* frame = (const float*)d_in[1];   // [4096]
  const float* Wq = (const float*)d_in[2];
  const float* bq = (const float*)d_in[3];
  const float* Wk = (const float*)d_in[4];
  const float* bk = (const float*)d_in[5];
  const float* Wv = (const float*)d_in[6];
  const float* bv = (const float*)d_in[7];
  const float* alibi = (const float*)d_in[8];
  float* out = (float*)d_out;                   // [4][2048][4096]

  const size_t NEED_BATCHED = (size_t)3072 * 1024 * 2 + 4096 +
                              4 * (4 * XB_STRIDE * 2) + 4 * SC_STRIDE * 4 + 2048;
  int NB = (ws_size >= NEED_BATCHED) ? 4 : 1;

  char* p = (char*)d_ws;
  __bf16* Wt = (__bf16*)p;  p += (size_t)3072 * 1024 * 2;
  float* bcat = (float*)p;  p += 3072 * 4;                    p = align256(p);
  __bf16* xb = (__bf16*)p;  p += NB * XB_STRIDE * 2;          p = align256(p);
  __bf16* Qb = (__bf16*)p;  p += NB * XB_STRIDE * 2;          p = align256(p);
  __bf16* Kb = (__bf16*)p;  p += NB * XB_STRIDE * 2;          p = align256(p);
  __bf16* Vt = (__bf16*)p;  p += NB * XB_STRIDE * 2;          p = align256(p);
  float* sc = (float*)p;    // NB x [4096][4096] fp32; P aliased into row halves

  transpose_w_k<<<dim3(32, 32, 3), dim3(32, 8), 0, stream>>>(Wq, Wk, Wv, Wt);
  bcat_k<<<12, 256, 0, stream>>>(bq, bk, bv, bcat);
  copy_in_k<<<16384, 256, 0, stream>>>((const float4*)input, (float4*)out);

  for (int b0 = 0; b0 < 4; b0 += NB) {
    const float* inb = input + (size_t)b0 * XB_STRIDE;
    float* outb = out + (size_t)b0 * OUT_STRIDE + (size_t)1024 * 4096;
    transpose_x_k<<<dim3(128, 32, NB), dim3(32, 8), 0, stream>>>(inb, xb);
    qkv_gemm_k<<<dim3(12, 16, NB), 512, 0, stream>>>(xb, Wt, bcat, Qb, Kb, Vt);
    qk_gemm_k<<<dim3(16, 16, NB), 512, 0, stream>>>(Qb, Kb, sc);
    softmax_k<<<dim3(4096, NB), 256, 0, stream>>>(sc, frame, alibi);
    pv_gemm_k<<<dim3(32, 8, NB), 256, 0, stream>>>((const __bf16*)((char*)sc + 8192), Vt, outb);
  }
}